// Round 3
// baseline (270.012 us; speedup 1.0000x reference)
//
#include <hip/hip_runtime.h>

// MultiHeadSelfAttention: B=2, S=2048, D=1024, H=16, Dh=64, fp32 in/out.
// R17: barrier-free attention. R16 made each head's K/V (512KB) L2-resident
// on one XCD -> LDS staging is pure overhead (common-mistake #7). The kt
// loop now reads K/V MFMA fragments DIRECTLY from global (L1/L2-served),
// which deletes every __syncthreads/vmcnt-drain from the loop (the ~35%
// lockstep idle), all staging+swizzle VALU, and replaces the 16-cndmask
// + 4-ds_bpermute P-exchange with 4 v_permlane32_swap_b32.
// Fragment<->address mapping identical to the verified R16 LDS path:
//   kf[ks]   = K[kt*64 + st*32 + l31][ks*16 + h*8 ..+8]
//   vf[dt][ks]= V^T[dt*32 + l31][kt*64 + st*32 + ks*16 + h*8 ..+8]
// cast/qkv/out kernels byte-identical to R16 (controls).

#define T_TOK 4096
#define DM    1024
#define SQ    2048
#define NH    16
#define DH    64

typedef unsigned short u16;
typedef unsigned int   u32;
typedef __bf16 bf16x8 __attribute__((ext_vector_type(8)));
typedef float  f32x4  __attribute__((ext_vector_type(4)));
typedef float  f32x16 __attribute__((ext_vector_type(16)));
typedef u32    u32x4  __attribute__((ext_vector_type(4)));

__device__ __forceinline__ u16 f2bf(float f) {   // RNE fp32->bf16
  u32 u = __builtin_bit_cast(u32, f);
  u32 r = (u + 0x7FFFu + ((u >> 16) & 1u)) >> 16;
  return (u16)r;
}

#if __has_builtin(__builtin_amdgcn_cvt_pk_bf16_f32)
typedef __bf16 bf16x2 __attribute__((ext_vector_type(2)));
__device__ __forceinline__ u32 pk2bf(float a, float b) {
  bf16x2 h = __builtin_amdgcn_cvt_pk_bf16_f32(a, b);
  return __builtin_bit_cast(u32, h);
}
#else
__device__ __forceinline__ u32 pk2bf(float a, float b) {  // 1 instr on gfx950
  u32 r;
  asm("v_cvt_pk_bf16_f32 %0, %1, %2" : "=v"(r) : "v"(a), "v"(b));
  return r;
}
#endif

__device__ __forceinline__ void gld16(const void* g, void* l) {
  __builtin_amdgcn_global_load_lds(
      (const __attribute__((address_space(1))) u32*)g,
      (__attribute__((address_space(3))) u32*)l, 16, 0, 0);
}

// ---------------- k1: cast to bf16 ----------------
__global__ void cast_bf16_kernel(const float* __restrict__ x,
    const float* __restrict__ w0, const float* __restrict__ w1,
    const float* __restrict__ w2, const float* __restrict__ w3,
    u16* __restrict__ xb, u16* __restrict__ o0, u16* __restrict__ o1,
    u16* __restrict__ o2, u16* __restrict__ o3)
{
  const float* src; u16* dst; int n;
  switch (blockIdx.y) {
    case 0:  src = x;  dst = xb; n = T_TOK * DM; break;
    case 1:  src = w0; dst = o0; n = DM * DM; break;
    case 2:  src = w1; dst = o1; n = DM * DM; break;
    case 3:  src = w2; dst = o2; n = DM * DM; break;
    default: src = w3; dst = o3; n = DM * DM; break;
  }
  const int stride = gridDim.x * blockDim.x;
  for (int i = blockIdx.x * blockDim.x + threadIdx.x; i * 4 < n; i += stride) {
    float4 v = ((const float4*)src)[i];
    ushort4 o;
    o.x = f2bf(v.x); o.y = f2bf(v.y); o.z = f2bf(v.z); o.w = f2bf(v.w);
    ((ushort4*)dst)[i] = o;
  }
}

// ------------- shared 128x128 NT-GEMM core (K=1024, BK=64, swizzled) ---------
__device__ __forceinline__ void gemm_core_128x128(
    u16* lds, const u16* __restrict__ Ab, const u16* __restrict__ Bb,
    f32x4 acc[4][4])
{
  u16* As = lds;
  u16* Bs = lds + 8192;
  const int tid = threadIdx.x, lane = tid & 63, w = tid >> 6;
  const int waveM = w >> 1, waveN = w & 1;
  const int col = lane & 15, quad = lane >> 4;
  const int srow = lane >> 3;                  // 0..7
  const int sg0  = (lane & 7) ^ srow;          // swizzle, rb-part added below

  for (int k0 = 0; k0 < DM; k0 += 64) {
    #pragma unroll
    for (int i = 0; i < 4; ++i) {
      const int rb = w * 32 + i * 8;
      const int sg = sg0 ^ ((rb >> 3) & 3);
      gld16(Ab + (size_t)(rb + srow) * DM + k0 + sg * 8, &As[rb * 64]);
      gld16(Bb + (size_t)(rb + srow) * DM + k0 + sg * 8, &Bs[rb * 64]);
    }
    __syncthreads();
    #pragma unroll
    for (int c = 0; c < 2; ++c) {
      bf16x8 af[4], bg[4];
      #pragma unroll
      for (int i = 0; i < 4; ++i) {
        const int row = waveM * 64 + i * 16 + col;
        const int gp = (c * 4 + quad) ^ (row & 7) ^ ((row >> 3) & 3);
        af[i] = *(const bf16x8*)&As[row * 64 + gp * 8];
      }
      #pragma unroll
      for (int j = 0; j < 4; ++j) {
        const int row = waveN * 64 + j * 16 + col;
        const int gp = (c * 4 + quad) ^ (row & 7) ^ ((row >> 3) & 3);
        bg[j] = *(const bf16x8*)&Bs[row * 64 + gp * 8];
      }
      #pragma unroll
      for (int i = 0; i < 4; ++i) {
        #pragma unroll
        for (int j = 0; j < 4; ++j)
          acc[i][j] = __builtin_amdgcn_mfma_f32_16x16x32_bf16(af[i], bg[j], acc[i][j], 0, 0, 0);
      }
    }
    __syncthreads();
  }
}

// ------------- 128x64 NT-GEMM core (A=128 rows, B=64 rows, BK=64) ------------
__device__ __forceinline__ void gemm_core_128x64(
    u16* lds, const u16* __restrict__ Ab, const u16* __restrict__ Bb,
    f32x4 acc[4][2])
{
  u16* As = lds;            // [128][64]
  u16* Bs = lds + 8192;     // [64][64]
  const int tid = threadIdx.x, lane = tid & 63, w = tid >> 6;
  const int waveM = w >> 1, waveN = w & 1;
  const int col = lane & 15, quad = lane >> 4;
  const int srow = lane >> 3;
  const int sg0  = (lane & 7) ^ srow;

  for (int k0 = 0; k0 < DM; k0 += 64) {
    #pragma unroll
    for (int i = 0; i < 4; ++i) {
      const int rb = w * 32 + i * 8;
      const int sg = sg0 ^ ((rb >> 3) & 3);
      gld16(Ab + (size_t)(rb + srow) * DM + k0 + sg * 8, &As[rb * 64]);
    }
    #pragma unroll
    for (int i = 0; i < 2; ++i) {
      const int rb = w * 16 + i * 8;
      const int sg = sg0 ^ ((rb >> 3) & 3);
      gld16(Bb + (size_t)(rb + srow) * DM + k0 + sg * 8, &Bs[rb * 64]);
    }
    __syncthreads();
    #pragma unroll
    for (int c = 0; c < 2; ++c) {
      bf16x8 af[4], bg[2];
      #pragma unroll
      for (int i = 0; i < 4; ++i) {
        const int row = waveM * 64 + i * 16 + col;
        const int gp = (c * 4 + quad) ^ (row & 7) ^ ((row >> 3) & 3);
        af[i] = *(const bf16x8*)&As[row * 64 + gp * 8];
      }
      #pragma unroll
      for (int j = 0; j < 2; ++j) {
        const int row = waveN * 32 + j * 16 + col;
        const int gp = (c * 4 + quad) ^ (row & 7) ^ ((row >> 3) & 3);
        bg[j] = *(const bf16x8*)&Bs[row * 64 + gp * 8];
      }
      #pragma unroll
      for (int i = 0; i < 4; ++i) {
        #pragma unroll
        for (int j = 0; j < 2; ++j)
          acc[i][j] = __builtin_amdgcn_mfma_f32_16x16x32_bf16(af[i], bg[j], acc[i][j], 0, 0, 0);
      }
    }
    __syncthreads();
  }
}

// ---------------- k2: fused QKV projection ----------------
// grid (32, 8, 3) — token-block on x so XCD = token-group:
//   z=0/1: A = W rows (cb: 128 channels), B = x rows (tb: 128 tokens)
//   z=2:   A = x rows (tb),  B = Wv rows (cb) + transpose
__global__ __launch_bounds__(256) void gemm_qkv_kernel(
    const u16* __restrict__ xb,
    const u16* __restrict__ Wqb, const u16* __restrict__ Wkb, const u16* __restrict__ Wvb,
    const float* __restrict__ bq, const float* __restrict__ bk, const float* __restrict__ bv,
    u16* __restrict__ Qs, u16* __restrict__ Kh, u16* __restrict__ Vt)
{
  __shared__ __align__(16) u16 smem[128 * 136];  // 34 KB: As/Bs | tr (V path)
  u16* tr = smem;
  const int z = blockIdx.z;
  const int tb = blockIdx.x;                     // token-block (32)
  const int cb = blockIdx.y;                     // channel-block (8)
  const u16*   Wb   = (z == 0) ? Wqb : (z == 1) ? Wkb : Wvb;
  const float* bias = (z == 0) ? bq  : (z == 1) ? bk  : bv;
  const float scale = (z == 0) ? 0.18033688011112042f : 1.0f;  // log2(e)/8 for Q

  const int tid = threadIdx.x;
  const int lane = tid & 63, w = tid >> 6;
  const int waveM = w >> 1, waveN = w & 1;
  const int col = lane & 15, quad = lane >> 4;
  const f32x4 zf = {0.f, 0.f, 0.f, 0.f};

  f32x4 acc[4][4];
  #pragma unroll
  for (int i = 0; i < 4; ++i) {
    #pragma unroll
    for (int j = 0; j < 4; ++j) acc[i][j] = zf;
  }

  if (z == 2) {
    gemm_core_128x128(smem, xb + (size_t)(tb * 128) * DM,
                      Wb + (size_t)(cb * 128) * DM, acc);
    // core ends with __syncthreads(); As/Bs dead -> reuse as transpose tile
    #pragma unroll
    for (int j = 0; j < 4; ++j) {
      const int cl = waveN * 64 + j * 16 + col;
      const float bb = bias[cb * 128 + cl];
      #pragma unroll
      for (int i = 0; i < 4; ++i) {
        const int tl = waveM * 64 + i * 16 + quad * 4;
        ushort4 pk;
        pk.x = f2bf(acc[i][j][0] + bb); pk.y = f2bf(acc[i][j][1] + bb);
        pk.z = f2bf(acc[i][j][2] + bb); pk.w = f2bf(acc[i][j][3] + bb);
        *(ushort4*)&tr[cl * 136 + tl] = pk;
      }
    }
    __syncthreads();
    const int t0 = tb * 128;
    const int b = t0 >> 11, sBase = t0 & 2047;
    #pragma unroll
    for (int rep = 0; rep < 8; ++rep) {
      const int chunk = rep * 256 + tid;
      const int row = chunk >> 4, off = (chunk & 15) * 8;
      const int c = cb * 128 + row;
      const int h = c >> 6, d = c & 63;
      uint4 v = *(const uint4*)&tr[row * 136 + off];
      *(uint4*)&Vt[((size_t)(b * NH + h) * DH + d) * SQ + sBase + off] = v;
    }
  } else {
    gemm_core_128x128(smem, Wb + (size_t)(cb * 128) * DM,
                      xb + (size_t)(tb * 128) * DM, acc);
    u16* out = (z == 0) ? Qs : Kh;
    const int chBase  = cb * 128 + waveM * 64;   // A side = channels
    const int tokBase = tb * 128 + waveN * 64;   // B side = tokens
    #pragma unroll
    for (int i = 0; i < 4; ++i) {
      const int c0 = chBase + i * 16 + quad * 4;         // 4 consecutive d
      const int hh = c0 >> 6, d0 = c0 & 63;
      const float4 bb = *(const float4*)&bias[c0];
      #pragma unroll
      for (int j = 0; j < 4; ++j) {
        const int t = tokBase + j * 16 + col;
        const int b = t >> 11, s = t & 2047;
        ushort4 pk;
        pk.x = f2bf((acc[i][j][0] + bb.x) * scale);
        pk.y = f2bf((acc[i][j][1] + bb.y) * scale);
        pk.z = f2bf((acc[i][j][2] + bb.z) * scale);
        pk.w = f2bf((acc[i][j][3] + bb.w) * scale);
        *(ushort4*)&out[((size_t)(b * NH + hh) * SQ + s) * DH + d0] = pk;
      }
    }
  }
}

// ---------------- k4: flash attention, barrier-free, direct-global K/V ------
// grid (B*H, S/64) — bh on x so XCD = bh%8 (K/V L2-resident per R16).
// block 256 = 4 waves; wave w: qt = w&1 (q-half), st = w>>1 (s'-half).
// Per kt iter (NO __syncthreads, no LDS in loop):
//   kf[ks]    <- global K rows st*32+l31 (L1/L2 hit)
//   vf[dt][ks]<- global V^T rows dt*32+l31
//   S^T = K Q^T (4 MFMA) -> exp2 -> pk2bf -> P C->B via 4 permlane32_swap
//   ctx^T += V^T P^T (4 MFMA)
// LDS (33KB) only for the cross-wave epilogue reduction -> 4 blocks/CU.
__global__ __launch_bounds__(256, 4) void attn_kernel(
    const u16* __restrict__ Qs, const u16* __restrict__ Kh,
    const u16* __restrict__ Vt, u16* __restrict__ ctx)
{
  __shared__ __align__(16) char smem[33 * 1024];
  f32x4* red  = (f32x4*)smem;               // 32 KB epilogue reduction
  float* lred = (float*)(smem + 32768);     // 1 KB

  const int tid = threadIdx.x, lane = tid & 63, w = tid >> 6;
  const int l31 = lane & 31, h = lane >> 5;
  const int qt = w & 1, st = w >> 1;
  const int bh = blockIdx.x, q0 = blockIdx.y * 64;
  const u16* Qb = Qs + ((size_t)bh * SQ + q0) * DH;
  const u16* Kb = Kh + (size_t)bh * SQ * DH;
  const u16* Vb = Vt + (size_t)bh * DH * SQ;

  // Q B-frags (only this wave's q-half): n = q = q0+qt*32+l31, k = 16ks+8h+j
  bf16x8 qreg[4];
  #pragma unroll
  for (int ks = 0; ks < 4; ++ks)
    qreg[ks] = *(const bf16x8*)(Qb + (size_t)(qt * 32 + l31) * DH + ks * 16 + h * 8);

  // per-lane fragment base pointers (u16 units); bumped per kt tile
  const u16* Kp  = Kb + (size_t)(st * 32 + l31) * DH + h * 8;        // +64*DH/iter
  const u16* Vp0 = Vb + (size_t)l31 * SQ        + st * 32 + h * 8;   // +64/iter
  const u16* Vp1 = Vb + (size_t)(32 + l31) * SQ + st * 32 + h * 8;   // +64/iter

  f32x16 cacc[2];                    // [dt] partial ctx^T (64d x 32q)
  #pragma unroll
  for (int dt = 0; dt < 2; ++dt)
    #pragma unroll
    for (int e = 0; e < 16; ++e) cacc[dt][e] = 0.f;
  float l_s = 0.f;

  for (int kt = 0; kt < SQ / 64; ++kt) {
    // fragment loads, straight from cache (issue all 8 up front)
    bf16x8 kf0  = *(const bf16x8*)(Kp +  0);
    bf16x8 kf1  = *(const bf16x8*)(Kp + 16);
    bf16x8 kf2  = *(const bf16x8*)(Kp + 32);
    bf16x8 kf3  = *(const bf16x8*)(Kp + 48);
    bf16x8 vf00 = *(const bf16x8*)(Vp0 +  0);   // dt=0, ks=0
    bf16x8 vf01 = *(const bf16x8*)(Vp0 + 16);   // dt=0, ks=1
    bf16x8 vf10 = *(const bf16x8*)(Vp1 +  0);   // dt=1, ks=0
    bf16x8 vf11 = *(const bf16x8*)(Vp1 + 16);   // dt=1, ks=1
    Kp += 64 * DH; Vp0 += 64; Vp1 += 64;

    // S^T = K Q^T over wave's 32-s' slice
    f32x16 sacc = {};
    __builtin_amdgcn_s_setprio(1);
    sacc = __builtin_amdgcn_mfma_f32_32x32x16_bf16(kf0, qreg[0], sacc, 0, 0, 0);
    sacc = __builtin_amdgcn_mfma_f32_32x32x16_bf16(kf1, qreg[1], sacc, 0, 0, 0);
    sacc = __builtin_amdgcn_mfma_f32_32x32x16_bf16(kf2, qreg[2], sacc, 0, 0, 0);
    sacc = __builtin_amdgcn_mfma_f32_32x32x16_bf16(kf3, qreg[3], sacc, 0, 0, 0);
    __builtin_amdgcn_s_setprio(0);

    // softmax p = exp2(s); Pp[rg][u] covers s'loc = 8rg + 4h + 2u + {0,1}
    u32 Pp[4][2];
    {
      float p[16];
      #pragma unroll
      for (int e = 0; e < 16; ++e)
        p[e] = __builtin_amdgcn_exp2f(sacc[e]);
      float t0 = (p[0] + p[1]) + (p[2] + p[3]);
      float t1 = (p[4] + p[5]) + (p[6] + p[7]);
      float t2 = (p[8] + p[9]) + (p[10] + p[11]);
      float t3 = (p[12] + p[13]) + (p[14] + p[15]);
      l_s += (t0 + t1) + (t2 + t3);
      #pragma unroll
      for (int rg = 0; rg < 4; ++rg) {
        Pp[rg][0] = pk2bf(p[4 * rg + 0], p[4 * rg + 1]);
        Pp[rg][1] = pk2bf(p[4 * rg + 2], p[4 * rg + 3]);
      }
    }

    // ctx^T += V^T(slice) P^T(slice): 2 ksteps over the 32 s'
    // P C->B redistribution: swap(Pp[2ks][u], Pp[2ks+1][u]) gives
    // fw.x/z (u=0) and fw.y/w (u=1) for BOTH lane halves in 1 instr each.
    __builtin_amdgcn_s_setprio(1);
    #pragma unroll
    for (int ks = 0; ks < 2; ++ks) {
      u32 a0 = Pp[2 * ks][0], b0 = Pp[2 * ks + 1][0];
      u32 a1 = Pp[2 * ks][1], b1 = Pp[2 * ks + 1][1];
      asm("v_permlane32_swap_b32 %0, %1" : "+v"(a0), "+v"(b0));
      asm("v_permlane32_swap_b32 %0, %1" : "+v"(a1), "+v"(b1));
      u32x4 fw;
      fw.x = a0; fw.y = a1; fw.z = b0; fw.w = b1;
      bf16x8 pf = __builtin_bit_cast(bf16x8, fw);
      cacc[0] = __builtin_amdgcn_mfma_f32_32x32x16_bf16(ks ? vf01 : vf00, pf, cacc[0], 0, 0, 0);
      cacc[1] = __builtin_amdgcn_mfma_f32_32x32x16_bf16(ks ? vf11 : vf10, pf, cacc[1], 0, 0, 0);
    }
    __builtin_amdgcn_s_setprio(0);
  }

  // ----- cross-wave reduction (2 sources per output) + epilogue -----
  float lq = l_s + __shfl_xor(l_s, 32, 64);
  if (h == 0) lred[w * 32 + l31] = lq;
  #pragma unroll
  for (int dt = 0; dt < 2; ++dt) {
    #pragma unroll
    for (int c = 0; c < 4; ++c) {
      f32x4 ch;
      ch[0] = cacc[dt][4 * c + 0]; ch[1] = cacc[dt][4 * c + 1];
      ch[2] = cacc[dt][4 * c + 2]; ch[3] = cacc[dt][4 * c + 3];
      red[((w * 2 + dt) * 4 + c) * 64 + lane] = ch;
    }
  }
  __syncthreads();
  // wave w outputs qt' = w&1, d-slice dt' = w>>1; sources: waves qt', qt'+2
  const int qt2 = w & 1, dt2 = w >> 1;
  const int b = bh >> 4, hd = bh & 15;
  const float lsum = lred[qt2 * 32 + l31] + lred[(2 + qt2) * 32 + l31];
  const float inv = 1.0f / lsum;
  const int s = q0 + qt2 * 32 + l31;
  #pragma unroll
  for (int c = 0; c < 4; ++c) {
    f32x4 sum = red[((qt2 * 2 + dt2) * 4 + c) * 64 + lane];
    sum += red[(((2 + qt2) * 2 + dt2) * 4 + c) * 64 + lane];
    const int d0 = dt2 * 32 + c * 8 + 4 * h;
    ushort4 pk;
    pk.x = f2bf(sum[0] * inv); pk.y = f2bf(sum[1] * inv);
    pk.z = f2bf(sum[2] * inv); pk.w = f2bf(sum[3] * inv);
    *(ushort4*)&ctx[(size_t)(b * SQ + s) * DM + hd * DH + d0] = pk;
  }
}

// -------- k5: output projection (128x64 tiles, BK=64 swizzled, fp32 out) -----
// grid (32, 16) — token-block on x so XCD = token-group (ctx panel
// fetched once per XCD group). A = 128 ctx tokens, B = 64 Wo channels.
__global__ __launch_bounds__(256) void gemm_out_kernel(
    const u16* __restrict__ ctx, const u16* __restrict__ Wob,
    const float* __restrict__ bo, float* __restrict__ out)
{
  __shared__ __align__(16) u16 smem[128 * 64 + 64 * 64];  // 24 KB
  const int tb = blockIdx.x;                 // token-block (32)
  const int cb = blockIdx.y;                 // channel-block (16)
  const int tid = threadIdx.x, lane = tid & 63, w = tid >> 6;
  const int waveM = w >> 1, waveN = w & 1;
  const int col = lane & 15, quad = lane >> 4;

  f32x4 acc[4][2];
  const f32x4 zf = {0.f, 0.f, 0.f, 0.f};
  #pragma unroll
  for (int i = 0; i < 4; ++i) {
    #pragma unroll
    for (int j = 0; j < 2; ++j) acc[i][j] = zf;
  }

  gemm_core_128x64(smem, ctx + (size_t)(tb * 128) * DM,
                   Wob + (size_t)(cb * 64) * DM, acc);

  const int rowBase = tb * 128 + waveM * 64;   // A side = tokens
  const int colBase = cb * 64 + waveN * 32;    // B side = channels
  #pragma unroll
  for (int j = 0; j < 2; ++j) {
    const int c = colBase + j * 16 + col;
    const float bb = bo[c];
    #pragma unroll
    for (int i = 0; i < 4; ++i) {
      #pragma unroll
      for (int r = 0; r < 4; ++r) {
        const int t = rowBase + i * 16 + quad * 4 + r;
        out[(size_t)t * DM + c] = acc[i][j][r] + bb;
      }
    }
  }
}

extern "C" void kernel_launch(void* const* d_in, const int* in_sizes, int n_in,
                              void* d_out, int out_size, void* d_ws, size_t ws_size,
                              hipStream_t stream) {
  const float* x  = (const float*)d_in[0];
  const float* Wq = (const float*)d_in[1];
  const float* bq = (const float*)d_in[2];
  const float* Wk = (const float*)d_in[3];
  const float* bk = (const float*)d_in[4];
  const float* Wv = (const float*)d_in[5];
  const float* bv = (const float*)d_in[6];
  const float* Wo = (const float*)d_in[7];
  const float* bo = (const float*)d_in[8];

  char* ws = (char*)d_ws;                  // 40 MB used
  u16* xb  = (u16*)(ws);                   // 8 MB  (reused as ctx after QKV)
  u16* Wqb = (u16*)(ws + (8ull  << 20));   // 2 MB
  u16* Wkb = (u16*)(ws + (10ull << 20));   // 2 MB
  u16* Wvb = (u16*)(ws + (12ull << 20));   // 2 MB
  u16* Wob = (u16*)(ws + (14ull << 20));   // 2 MB
  u16* Qs  = (u16*)(ws + (16ull << 20));   // 8 MB  [b,h,s,d], pre-scaled
  u16* Kh  = (u16*)(ws + (24ull << 20));   // 8 MB  [b,h,s,d]
  u16* Vt  = (u16*)(ws + (32ull << 20));   // 8 MB  [b,h,d,s]
  u16* ctx = xb;                           // alias: xb dead after QKV GEMM

  cast_bf16_kernel<<<dim3(256, 5), 256, 0, stream>>>(x, Wq, Wk, Wv, Wo,
                                                     xb, Wqb, Wkb, Wvb, Wob);
  gemm_qkv_kernel<<<dim3(32, 8, 3), 256, 0, stream>>>(xb, Wqb, Wkb, Wvb,
                                                      bq, bk, bv, Qs, Kh, Vt);
  attn_kernel<<<dim3(32, 32), 256, 0, stream>>>(Qs, Kh, Vt, ctx);
  gemm_out_kernel<<<dim3(32, 16), 256, 0, stream>>>(ctx, Wob, bo, (float*)d_out);
  (void)in_sizes; (void)n_in; (void)out_size; (void)ws_size;
}

// Round 4
// 203.173 us; speedup vs baseline: 1.3290x; 1.3290x over previous
//
#include <hip/hip_runtime.h>

// MultiHeadSelfAttention: B=2, S=2048, D=1024, H=16, Dh=64, fp32 in/out.
// R18: wave-private barrier-free attention. R17's direct-global failed on
// scattered-load latency (MfmaUtil 10%); R16's LDS version pays ~35%/iter
// barrier lockstep. Insight: each wave's MFMA reads are wave-private
// (K rows st*32..+32; V^T cols st*32..+32) -> no sharing -> no barriers.
// Per wave: private K/V slices (4KB+4KB), double-buffered (64KB LDS total),
// staged via coalesced gld16 (global src is per-lane: V side gathers rows),
// synced only by per-wave counted s_waitcnt vmcnt(8) (T4). Epilogue
// reduction relocated into each wave's own arena (no cross-wave clobber
// before the single epilogue __syncthreads). P-exchange keeps R17's
// verified v_permlane32_swap. cast/qkv/out byte-identical to R16.

#define T_TOK 4096
#define DM    1024
#define SQ    2048
#define NH    16
#define DH    64

typedef unsigned short u16;
typedef unsigned int   u32;
typedef __bf16 bf16x8 __attribute__((ext_vector_type(8)));
typedef float  f32x4  __attribute__((ext_vector_type(4)));
typedef float  f32x16 __attribute__((ext_vector_type(16)));
typedef u32    u32x4  __attribute__((ext_vector_type(4)));

__device__ __forceinline__ u16 f2bf(float f) {   // RNE fp32->bf16
  u32 u = __builtin_bit_cast(u32, f);
  u32 r = (u + 0x7FFFu + ((u >> 16) & 1u)) >> 16;
  return (u16)r;
}

#if __has_builtin(__builtin_amdgcn_cvt_pk_bf16_f32)
typedef __bf16 bf16x2 __attribute__((ext_vector_type(2)));
__device__ __forceinline__ u32 pk2bf(float a, float b) {
  bf16x2 h = __builtin_amdgcn_cvt_pk_bf16_f32(a, b);
  return __builtin_bit_cast(u32, h);
}
#else
__device__ __forceinline__ u32 pk2bf(float a, float b) {  // 1 instr on gfx950
  u32 r;
  asm("v_cvt_pk_bf16_f32 %0, %1, %2" : "=v"(r) : "v"(a), "v"(b));
  return r;
}
#endif

__device__ __forceinline__ void gld16(const void* g, void* l) {
  __builtin_amdgcn_global_load_lds(
      (const __attribute__((address_space(1))) u32*)g,
      (__attribute__((address_space(3))) u32*)l, 16, 0, 0);
}

// ---------------- k1: cast to bf16 ----------------
__global__ void cast_bf16_kernel(const float* __restrict__ x,
    const float* __restrict__ w0, const float* __restrict__ w1,
    const float* __restrict__ w2, const float* __restrict__ w3,
    u16* __restrict__ xb, u16* __restrict__ o0, u16* __restrict__ o1,
    u16* __restrict__ o2, u16* __restrict__ o3)
{
  const float* src; u16* dst; int n;
  switch (blockIdx.y) {
    case 0:  src = x;  dst = xb; n = T_TOK * DM; break;
    case 1:  src = w0; dst = o0; n = DM * DM; break;
    case 2:  src = w1; dst = o1; n = DM * DM; break;
    case 3:  src = w2; dst = o2; n = DM * DM; break;
    default: src = w3; dst = o3; n = DM * DM; break;
  }
  const int stride = gridDim.x * blockDim.x;
  for (int i = blockIdx.x * blockDim.x + threadIdx.x; i * 4 < n; i += stride) {
    float4 v = ((const float4*)src)[i];
    ushort4 o;
    o.x = f2bf(v.x); o.y = f2bf(v.y); o.z = f2bf(v.z); o.w = f2bf(v.w);
    ((ushort4*)dst)[i] = o;
  }
}

// ------------- shared 128x128 NT-GEMM core (K=1024, BK=64, swizzled) ---------
__device__ __forceinline__ void gemm_core_128x128(
    u16* lds, const u16* __restrict__ Ab, const u16* __restrict__ Bb,
    f32x4 acc[4][4])
{
  u16* As = lds;
  u16* Bs = lds + 8192;
  const int tid = threadIdx.x, lane = tid & 63, w = tid >> 6;
  const int waveM = w >> 1, waveN = w & 1;
  const int col = lane & 15, quad = lane >> 4;
  const int srow = lane >> 3;                  // 0..7
  const int sg0  = (lane & 7) ^ srow;          // swizzle, rb-part added below

  for (int k0 = 0; k0 < DM; k0 += 64) {
    #pragma unroll
    for (int i = 0; i < 4; ++i) {
      const int rb = w * 32 + i * 8;
      const int sg = sg0 ^ ((rb >> 3) & 3);
      gld16(Ab + (size_t)(rb + srow) * DM + k0 + sg * 8, &As[rb * 64]);
      gld16(Bb + (size_t)(rb + srow) * DM + k0 + sg * 8, &Bs[rb * 64]);
    }
    __syncthreads();
    #pragma unroll
    for (int c = 0; c < 2; ++c) {
      bf16x8 af[4], bg[4];
      #pragma unroll
      for (int i = 0; i < 4; ++i) {
        const int row = waveM * 64 + i * 16 + col;
        const int gp = (c * 4 + quad) ^ (row & 7) ^ ((row >> 3) & 3);
        af[i] = *(const bf16x8*)&As[row * 64 + gp * 8];
      }
      #pragma unroll
      for (int j = 0; j < 4; ++j) {
        const int row = waveN * 64 + j * 16 + col;
        const int gp = (c * 4 + quad) ^ (row & 7) ^ ((row >> 3) & 3);
        bg[j] = *(const bf16x8*)&Bs[row * 64 + gp * 8];
      }
      #pragma unroll
      for (int i = 0; i < 4; ++i) {
        #pragma unroll
        for (int j = 0; j < 4; ++j)
          acc[i][j] = __builtin_amdgcn_mfma_f32_16x16x32_bf16(af[i], bg[j], acc[i][j], 0, 0, 0);
      }
    }
    __syncthreads();
  }
}

// ------------- 128x64 NT-GEMM core (A=128 rows, B=64 rows, BK=64) ------------
__device__ __forceinline__ void gemm_core_128x64(
    u16* lds, const u16* __restrict__ Ab, const u16* __restrict__ Bb,
    f32x4 acc[4][2])
{
  u16* As = lds;            // [128][64]
  u16* Bs = lds + 8192;     // [64][64]
  const int tid = threadIdx.x, lane = tid & 63, w = tid >> 6;
  const int waveM = w >> 1, waveN = w & 1;
  const int col = lane & 15, quad = lane >> 4;
  const int srow = lane >> 3;
  const int sg0  = (lane & 7) ^ srow;

  for (int k0 = 0; k0 < DM; k0 += 64) {
    #pragma unroll
    for (int i = 0; i < 4; ++i) {
      const int rb = w * 32 + i * 8;
      const int sg = sg0 ^ ((rb >> 3) & 3);
      gld16(Ab + (size_t)(rb + srow) * DM + k0 + sg * 8, &As[rb * 64]);
    }
    #pragma unroll
    for (int i = 0; i < 2; ++i) {
      const int rb = w * 16 + i * 8;
      const int sg = sg0 ^ ((rb >> 3) & 3);
      gld16(Bb + (size_t)(rb + srow) * DM + k0 + sg * 8, &Bs[rb * 64]);
    }
    __syncthreads();
    #pragma unroll
    for (int c = 0; c < 2; ++c) {
      bf16x8 af[4], bg[2];
      #pragma unroll
      for (int i = 0; i < 4; ++i) {
        const int row = waveM * 64 + i * 16 + col;
        const int gp = (c * 4 + quad) ^ (row & 7) ^ ((row >> 3) & 3);
        af[i] = *(const bf16x8*)&As[row * 64 + gp * 8];
      }
      #pragma unroll
      for (int j = 0; j < 2; ++j) {
        const int row = waveN * 32 + j * 16 + col;
        const int gp = (c * 4 + quad) ^ (row & 7) ^ ((row >> 3) & 3);
        bg[j] = *(const bf16x8*)&Bs[row * 64 + gp * 8];
      }
      #pragma unroll
      for (int i = 0; i < 4; ++i) {
        #pragma unroll
        for (int j = 0; j < 2; ++j)
          acc[i][j] = __builtin_amdgcn_mfma_f32_16x16x32_bf16(af[i], bg[j], acc[i][j], 0, 0, 0);
      }
    }
    __syncthreads();
  }
}

// ---------------- k2: fused QKV projection ----------------
// grid (32, 8, 3) — token-block on x so XCD = token-group:
//   z=0/1: A = W rows (cb: 128 channels), B = x rows (tb: 128 tokens)
//   z=2:   A = x rows (tb),  B = Wv rows (cb) + transpose
__global__ __launch_bounds__(256) void gemm_qkv_kernel(
    const u16* __restrict__ xb,
    const u16* __restrict__ Wqb, const u16* __restrict__ Wkb, const u16* __restrict__ Wvb,
    const float* __restrict__ bq, const float* __restrict__ bk, const float* __restrict__ bv,
    u16* __restrict__ Qs, u16* __restrict__ Kh, u16* __restrict__ Vt)
{
  __shared__ __align__(16) u16 smem[128 * 136];  // 34 KB: As/Bs | tr (V path)
  u16* tr = smem;
  const int z = blockIdx.z;
  const int tb = blockIdx.x;                     // token-block (32)
  const int cb = blockIdx.y;                     // channel-block (8)
  const u16*   Wb   = (z == 0) ? Wqb : (z == 1) ? Wkb : Wvb;
  const float* bias = (z == 0) ? bq  : (z == 1) ? bk  : bv;
  const float scale = (z == 0) ? 0.18033688011112042f : 1.0f;  // log2(e)/8 for Q

  const int tid = threadIdx.x;
  const int lane = tid & 63, w = tid >> 6;
  const int waveM = w >> 1, waveN = w & 1;
  const int col = lane & 15, quad = lane >> 4;
  const f32x4 zf = {0.f, 0.f, 0.f, 0.f};

  f32x4 acc[4][4];
  #pragma unroll
  for (int i = 0; i < 4; ++i) {
    #pragma unroll
    for (int j = 0; j < 4; ++j) acc[i][j] = zf;
  }

  if (z == 2) {
    gemm_core_128x128(smem, xb + (size_t)(tb * 128) * DM,
                      Wb + (size_t)(cb * 128) * DM, acc);
    // core ends with __syncthreads(); As/Bs dead -> reuse as transpose tile
    #pragma unroll
    for (int j = 0; j < 4; ++j) {
      const int cl = waveN * 64 + j * 16 + col;
      const float bb = bias[cb * 128 + cl];
      #pragma unroll
      for (int i = 0; i < 4; ++i) {
        const int tl = waveM * 64 + i * 16 + quad * 4;
        ushort4 pk;
        pk.x = f2bf(acc[i][j][0] + bb); pk.y = f2bf(acc[i][j][1] + bb);
        pk.z = f2bf(acc[i][j][2] + bb); pk.w = f2bf(acc[i][j][3] + bb);
        *(ushort4*)&tr[cl * 136 + tl] = pk;
      }
    }
    __syncthreads();
    const int t0 = tb * 128;
    const int b = t0 >> 11, sBase = t0 & 2047;
    #pragma unroll
    for (int rep = 0; rep < 8; ++rep) {
      const int chunk = rep * 256 + tid;
      const int row = chunk >> 4, off = (chunk & 15) * 8;
      const int c = cb * 128 + row;
      const int h = c >> 6, d = c & 63;
      uint4 v = *(const uint4*)&tr[row * 136 + off];
      *(uint4*)&Vt[((size_t)(b * NH + h) * DH + d) * SQ + sBase + off] = v;
    }
  } else {
    gemm_core_128x128(smem, Wb + (size_t)(cb * 128) * DM,
                      xb + (size_t)(tb * 128) * DM, acc);
    u16* out = (z == 0) ? Qs : Kh;
    const int chBase  = cb * 128 + waveM * 64;   // A side = channels
    const int tokBase = tb * 128 + waveN * 64;   // B side = tokens
    #pragma unroll
    for (int i = 0; i < 4; ++i) {
      const int c0 = chBase + i * 16 + quad * 4;         // 4 consecutive d
      const int hh = c0 >> 6, d0 = c0 & 63;
      const float4 bb = *(const float4*)&bias[c0];
      #pragma unroll
      for (int j = 0; j < 4; ++j) {
        const int t = tokBase + j * 16 + col;
        const int b = t >> 11, s = t & 2047;
        ushort4 pk;
        pk.x = f2bf((acc[i][j][0] + bb.x) * scale);
        pk.y = f2bf((acc[i][j][1] + bb.y) * scale);
        pk.z = f2bf((acc[i][j][2] + bb.z) * scale);
        pk.w = f2bf((acc[i][j][3] + bb.w) * scale);
        *(ushort4*)&out[((size_t)(b * NH + hh) * SQ + s) * DH + d0] = pk;
      }
    }
  }
}

// -------- k4: flash attention, wave-private LDS slices, barrier-free --------
// grid (B*H, S/64) — bh on x so XCD = bh%8 (K/V L2-resident).
// block 256 = 4 waves; wave w: qt = w&1 (q-half), st = w>>1 (s'-half).
// Each wave owns a 16KB LDS arena: K slice [2 bufs][32 rows][64 k] (swz
// slot = grp^(r&7)) + V slice [2 bufs][64 rows x 32 cols] (paired-row
// layout: byte = (r>>1)*128 + (r&1)*64 + (g^((r>>1)&3))*16). Staged by
// 8 gld16/iter (per-lane global src handles the V row-gather), consumed
// after a per-wave counted s_waitcnt vmcnt(8). NO __syncthreads in loop.
// Epilogue reduction reuses each wave's own arena (safe w/o loop sync).
__global__ __launch_bounds__(256, 2) void attn_kernel(
    const u16* __restrict__ Qs, const u16* __restrict__ Kh,
    const u16* __restrict__ Vt, u16* __restrict__ ctx)
{
  __shared__ __align__(16) char smem[64 * 1024];   // 4 waves x 16KB arena

  const int tid = threadIdx.x, lane = tid & 63, w = tid >> 6;
  const int l31 = lane & 31, h = lane >> 5;
  const int qt = w & 1, st = w >> 1;
  const int bh = blockIdx.x, q0 = blockIdx.y * 64;
  const u16* Qb = Qs + ((size_t)bh * SQ + q0) * DH;
  const u16* Kb = Kh + ((size_t)bh * SQ + st * 32) * DH;   // wave K row base
  const u16* Vb = Vt + (size_t)bh * DH * SQ + st * 32;     // wave V col base

  u16* KL = (u16*)(smem + w * 16384);          // [2][2048] u16 (2 x 4KB)
  u16* VL = (u16*)(smem + w * 16384 + 8192);   // [2][2048] u16 (2 x 4KB)

  // staging lane decomposition (verified bijections, see header comment)
  const int krow = lane >> 3;                  // K row-in-group 0..7
  const int ksg  = (lane & 7) ^ krow;          // K source grp (inv swizzle)
  const int vrow = 2 * (lane >> 3) + ((lane >> 2) & 1);  // V row-in-group 0..15
  const int vg   = (lane & 3) ^ ((lane >> 3) & 3);       // V source grp

  // Q B-frags: n = q = q0+qt*32+l31, k = 16ks+8h+j
  bf16x8 qreg[4];
  #pragma unroll
  for (int ks = 0; ks < 4; ++ks)
    qreg[ks] = *(const bf16x8*)(Qb + (size_t)(qt * 32 + l31) * DH + ks * 16 + h * 8);

  // read-side precomputed offsets (u16 units)
  const int krd = l31 * 64;                      // + ((2ks+h)^(l31&7))*8
  const int vrd0 = (l31 >> 1) * 64 + (l31 & 1) * 32;           // dt=0
  const int vrd1 = (16 + (l31 >> 1)) * 64 + (l31 & 1) * 32;    // dt=1 (rv=32+l31)
  const int vkey0 = (l31 >> 1) & 3;              // (rv>>1)&3 for dt=0
  // dt=1: rv>>1 = 16 + (l31>>1) -> &3 identical (16%4==0)

  f32x16 cacc[2];                    // [dt] partial ctx^T (64d x 32q)
  #pragma unroll
  for (int dt = 0; dt < 2; ++dt)
    #pragma unroll
    for (int e = 0; e < 16; ++e) cacc[dt][e] = 0.f;
  float l_s = 0.f;

  #define STAGE(buf, kt_) do {                                              \
    u16* kd = KL + (buf) * 2048;                                            \
    u16* vd = VL + (buf) * 2048;                                            \
    const u16* ksp = Kb + (size_t)((kt_) * 64) * DH;                        \
    const u16* vsp = Vb + (kt_) * 64;                                       \
    _Pragma("unroll")                                                       \
    for (int i = 0; i < 4; ++i)                                             \
      gld16(ksp + (size_t)(i * 8 + krow) * DH + ksg * 8, kd + i * 512);     \
    _Pragma("unroll")                                                       \
    for (int j = 0; j < 4; ++j)                                             \
      gld16(vsp + (size_t)(16 * j + vrow) * SQ + vg * 8, vd + j * 512);     \
  } while (0)

  STAGE(0, 0);

  for (int kt = 0; kt < SQ / 64; ++kt) {
    const int cur = kt & 1;
    if (kt + 1 < SQ / 64) {
      STAGE(cur ^ 1, kt + 1);
      asm volatile("s_waitcnt vmcnt(8)" ::: "memory");
    } else {
      asm volatile("s_waitcnt vmcnt(0)" ::: "memory");
    }
    const u16* Kt = KL + cur * 2048;
    const u16* Vl = VL + cur * 2048;

    // S^T = K Q^T over wave's 32-s' slice
    bf16x8 kf[4];
    #pragma unroll
    for (int ks = 0; ks < 4; ++ks)
      kf[ks] = *(const bf16x8*)&Kt[krd + (((2 * ks + h) ^ (l31 & 7)) * 8)];
    f32x16 sacc = {};
    __builtin_amdgcn_s_setprio(1);
    sacc = __builtin_amdgcn_mfma_f32_32x32x16_bf16(kf[0], qreg[0], sacc, 0, 0, 0);
    sacc = __builtin_amdgcn_mfma_f32_32x32x16_bf16(kf[1], qreg[1], sacc, 0, 0, 0);
    sacc = __builtin_amdgcn_mfma_f32_32x32x16_bf16(kf[2], qreg[2], sacc, 0, 0, 0);
    sacc = __builtin_amdgcn_mfma_f32_32x32x16_bf16(kf[3], qreg[3], sacc, 0, 0, 0);
    __builtin_amdgcn_s_setprio(0);

    // softmax p = exp2(s)
    u32 Pp[4][2];
    {
      float p[16];
      #pragma unroll
      for (int e = 0; e < 16; ++e)
        p[e] = __builtin_amdgcn_exp2f(sacc[e]);
      float t0 = (p[0] + p[1]) + (p[2] + p[3]);
      float t1 = (p[4] + p[5]) + (p[6] + p[7]);
      float t2 = (p[8] + p[9]) + (p[10] + p[11]);
      float t3 = (p[12] + p[13]) + (p[14] + p[15]);
      l_s += (t0 + t1) + (t2 + t3);
      #pragma unroll
      for (int rg = 0; rg < 4; ++rg) {
        Pp[rg][0] = pk2bf(p[4 * rg + 0], p[4 * rg + 1]);
        Pp[rg][1] = pk2bf(p[4 * rg + 2], p[4 * rg + 3]);
      }
    }

    // ctx^T += V^T(slice) P^T(slice)
    __builtin_amdgcn_s_setprio(1);
    #pragma unroll
    for (int ks = 0; ks < 2; ++ks) {
      u32 a0 = Pp[2 * ks][0], b0 = Pp[2 * ks + 1][0];
      u32 a1 = Pp[2 * ks][1], b1 = Pp[2 * ks + 1][1];
      asm("v_permlane32_swap_b32 %0, %1" : "+v"(a0), "+v"(b0));
      asm("v_permlane32_swap_b32 %0, %1" : "+v"(a1), "+v"(b1));
      u32x4 fw;
      fw.x = a0; fw.y = a1; fw.z = b0; fw.w = b1;
      bf16x8 pf = __builtin_bit_cast(bf16x8, fw);
      const int sl = ((2 * ks + h) ^ vkey0) * 8;
      bf16x8 vf0 = *(const bf16x8*)&Vl[vrd0 + sl];
      bf16x8 vf1 = *(const bf16x8*)&Vl[vrd1 + sl];
      cacc[0] = __builtin_amdgcn_mfma_f32_32x32x16_bf16(vf0, pf, cacc[0], 0, 0, 0);
      cacc[1] = __builtin_amdgcn_mfma_f32_32x32x16_bf16(vf1, pf, cacc[1], 0, 0, 0);
    }
    __builtin_amdgcn_s_setprio(0);
  }
  #undef STAGE

  // ----- cross-wave reduction + epilogue (arena-local slabs) -----
  f32x4* redw = (f32x4*)(smem + w * 16384);          // own arena, 8KB
  float* lredw = (float*)(smem + w * 16384 + 8192);  // own arena, 128B
  float lq = l_s + __shfl_xor(l_s, 32, 64);
  if (h == 0) lredw[l31] = lq;
  #pragma unroll
  for (int dt = 0; dt < 2; ++dt) {
    #pragma unroll
    for (int c = 0; c < 4; ++c) {
      f32x4 ch;
      ch[0] = cacc[dt][4 * c + 0]; ch[1] = cacc[dt][4 * c + 1];
      ch[2] = cacc[dt][4 * c + 2]; ch[3] = cacc[dt][4 * c + 3];
      redw[(dt * 4 + c) * 64 + lane] = ch;
    }
  }
  __syncthreads();
  // wave w outputs qt' = w&1, d-slice dt' = w>>1; sources: waves qt', qt'+2
  const int qt2 = w & 1, dt2 = w >> 1;
  const f32x4* redA = (const f32x4*)(smem + qt2 * 16384);
  const f32x4* redB = (const f32x4*)(smem + (2 + qt2) * 16384);
  const float* lrA = (const float*)(smem + qt2 * 16384 + 8192);
  const float* lrB = (const float*)(smem + (2 + qt2) * 16384 + 8192);
  const int b = bh >> 4, hd = bh & 15;
  const float lsum = lrA[l31] + lrB[l31];
  const float inv = 1.0f / lsum;
  const int s = q0 + qt2 * 32 + l31;
  #pragma unroll
  for (int c = 0; c < 4; ++c) {
    f32x4 sum = redA[(dt2 * 4 + c) * 64 + lane];
    sum += redB[(dt2 * 4 + c) * 64 + lane];
    const int d0 = dt2 * 32 + c * 8 + 4 * h;
    ushort4 pk;
    pk.x = f2bf(sum[0] * inv); pk.y = f2bf(sum[1] * inv);
    pk.z = f2bf(sum[2] * inv); pk.w = f2bf(sum[3] * inv);
    *(ushort4*)&ctx[(size_t)(b * SQ + s) * DM + hd * DH + d0] = pk;
  }
}

// -------- k5: output projection (128x64 tiles, BK=64 swizzled, fp32 out) -----
// grid (32, 16) — token-block on x so XCD = token-group.
__global__ __launch_bounds__(256) void gemm_out_kernel(
    const u16* __restrict__ ctx, const u16* __restrict__ Wob,
    const float* __restrict__ bo, float* __restrict__ out)
{
  __shared__ __align__(16) u16 smem[128 * 64 + 64 * 64];  // 24 KB
  const int tb = blockIdx.x;                 // token-block (32)
  const int cb = blockIdx.y;                 // channel-block (16)
  const int tid = threadIdx.x, lane = tid & 63, w = tid >> 6;
  const int waveM = w >> 1, waveN = w & 1;
  const int col = lane & 15, quad = lane >> 4;

  f32x4 acc[4][2];
  const f32x4 zf = {0.f, 0.f, 0.f, 0.f};
  #pragma unroll
  for (int i = 0; i < 4; ++i) {
    #pragma unroll
    for (int j = 0; j < 2; ++j) acc[i][j] = zf;
  }

  gemm_core_128x64(smem, ctx + (size_t)(tb * 128) * DM,
                   Wob + (size_t)(cb * 64) * DM, acc);

  const int rowBase = tb * 128 + waveM * 64;   // A side = tokens
  const int colBase = cb * 64 + waveN * 32;    // B side = channels
  #pragma unroll
  for (int j = 0; j < 2; ++j) {
    const int c = colBase + j * 16 + col;
    const float bb = bo[c];
    #pragma unroll
    for (int i = 0; i < 4; ++i) {
      #pragma unroll
      for (int r = 0; r < 4; ++r) {
        const int t = rowBase + i * 16 + quad * 4 + r;
        out[(size_t)t * DM + c] = acc[i][j][r] + bb;
      }
    }
  }
}

extern "C" void kernel_launch(void* const* d_in, const int* in_sizes, int n_in,
                              void* d_out, int out_size, void* d_ws, size_t ws_size,
                              hipStream_t stream) {
  const float* x  = (const float*)d_in[0];
  const float* Wq = (const float*)d_in[1];
  const float* bq = (const float*)d_in[2];
  const float* Wk = (const float*)d_in[3];
  const float* bk = (const float*)d_in[4];
  const float* Wv = (const float*)d_in[5];
  const float* bv = (const float*)d_in[6];
  const float* Wo = (const float*)d_in[7];
  const float* bo = (const float*)d_in[8];

  char* ws = (char*)d_ws;                  // 40 MB used
  u16* xb  = (u16*)(ws);                   // 8 MB  (reused as ctx after QKV)
  u16* Wqb = (u16*)(ws + (8ull  << 20));   // 2 MB
  u16* Wkb = (u16*)(ws + (10ull << 20));   // 2 MB
  u16* Wvb = (u16*)(ws + (12ull << 20));   // 2 MB
  u16* Wob = (u16*)(ws + (14ull << 20));   // 2 MB
  u16* Qs  = (u16*)(ws + (16ull << 20));   // 8 MB  [b,h,s,d], pre-scaled
  u16* Kh  = (u16*)(ws + (24ull << 20));   // 8 MB  [b,h,s,d]
  u16* Vt  = (u16*)(ws + (32ull << 20));   // 8 MB  [b,h,d,s]
  u16* ctx = xb;                           // alias: xb dead after QKV GEMM

  cast_bf16_kernel<<<dim3(256, 5), 256, 0, stream>>>(x, Wq, Wk, Wv, Wo,
                                                     xb, Wqb, Wkb, Wvb, Wob);
  gemm_qkv_kernel<<<dim3(32, 8, 3), 256, 0, stream>>>(xb, Wqb, Wkb, Wvb,
                                                      bq, bk, bv, Qs, Kh, Vt);
  attn_kernel<<<dim3(32, 32), 256, 0, stream>>>(Qs, Kh, Vt, ctx);
  gemm_out_kernel<<<dim3(32, 16), 256, 0, stream>>>(ctx, Wob, bo, (float*)d_out);
  (void)in_sizes; (void)n_in; (void)out_size; (void)ws_size;
}

// Round 5
// 188.781 us; speedup vs baseline: 1.4303x; 1.0762x over previous
//
#include <hip/hip_runtime.h>

// MultiHeadSelfAttention: B=2, S=2048, D=1024, H=16, Dh=64, fp32 in/out.
// R19: (a) attn REVERTED byte-for-byte to R16 (proven 54.9us, 0 bank
// conflicts, 4 blocks/CU; R17/R18 barrier-removal both regressed — the
// prefetch has a full iteration to land so R16's drain is already free).
// (b) qkv Q+K FUSION: z=0 now computes BOTH Q and K 128x128 tiles from one
// staged x-tile (3 panels staged per 2 output tiles instead of 4; 64 MFMA
// per K-step per wave vs 32) — attacks the 2-barrier staging drain, which
// is the only structural inefficiency visible in qkv. Grid (32,8,2).
// cast / out kernels byte-identical to R16 (controls).

#define T_TOK 4096
#define DM    1024
#define SQ    2048
#define NH    16
#define DH    64

typedef unsigned short u16;
typedef unsigned int   u32;
typedef __bf16 bf16x8 __attribute__((ext_vector_type(8)));
typedef float  f32x4  __attribute__((ext_vector_type(4)));
typedef float  f32x16 __attribute__((ext_vector_type(16)));
typedef u32    u32x4  __attribute__((ext_vector_type(4)));

__device__ __forceinline__ u16 f2bf(float f) {   // RNE fp32->bf16
  u32 u = __builtin_bit_cast(u32, f);
  u32 r = (u + 0x7FFFu + ((u >> 16) & 1u)) >> 16;
  return (u16)r;
}

#if __has_builtin(__builtin_amdgcn_cvt_pk_bf16_f32)
typedef __bf16 bf16x2 __attribute__((ext_vector_type(2)));
__device__ __forceinline__ u32 pk2bf(float a, float b) {
  bf16x2 h = __builtin_amdgcn_cvt_pk_bf16_f32(a, b);
  return __builtin_bit_cast(u32, h);
}
#else
__device__ __forceinline__ u32 pk2bf(float a, float b) {  // 1 instr on gfx950
  u32 r;
  asm("v_cvt_pk_bf16_f32 %0, %1, %2" : "=v"(r) : "v"(a), "v"(b));
  return r;
}
#endif

__device__ __forceinline__ void gld16(const void* g, void* l) {
  __builtin_amdgcn_global_load_lds(
      (const __attribute__((address_space(1))) u32*)g,
      (__attribute__((address_space(3))) u32*)l, 16, 0, 0);
}

// ---------------- k1: cast to bf16 ----------------
__global__ void cast_bf16_kernel(const float* __restrict__ x,
    const float* __restrict__ w0, const float* __restrict__ w1,
    const float* __restrict__ w2, const float* __restrict__ w3,
    u16* __restrict__ xb, u16* __restrict__ o0, u16* __restrict__ o1,
    u16* __restrict__ o2, u16* __restrict__ o3)
{
  const float* src; u16* dst; int n;
  switch (blockIdx.y) {
    case 0:  src = x;  dst = xb; n = T_TOK * DM; break;
    case 1:  src = w0; dst = o0; n = DM * DM; break;
    case 2:  src = w1; dst = o1; n = DM * DM; break;
    case 3:  src = w2; dst = o2; n = DM * DM; break;
    default: src = w3; dst = o3; n = DM * DM; break;
  }
  const int stride = gridDim.x * blockDim.x;
  for (int i = blockIdx.x * blockDim.x + threadIdx.x; i * 4 < n; i += stride) {
    float4 v = ((const float4*)src)[i];
    ushort4 o;
    o.x = f2bf(v.x); o.y = f2bf(v.y); o.z = f2bf(v.z); o.w = f2bf(v.w);
    ((ushort4*)dst)[i] = o;
  }
}

// ------------- shared 128x128 NT-GEMM core (K=1024, BK=64, swizzled) ---------
__device__ __forceinline__ void gemm_core_128x128(
    u16* lds, const u16* __restrict__ Ab, const u16* __restrict__ Bb,
    f32x4 acc[4][4])
{
  u16* As = lds;
  u16* Bs = lds + 8192;
  const int tid = threadIdx.x, lane = tid & 63, w = tid >> 6;
  const int waveM = w >> 1, waveN = w & 1;
  const int col = lane & 15, quad = lane >> 4;
  const int srow = lane >> 3;                  // 0..7
  const int sg0  = (lane & 7) ^ srow;          // swizzle, rb-part added below

  for (int k0 = 0; k0 < DM; k0 += 64) {
    #pragma unroll
    for (int i = 0; i < 4; ++i) {
      const int rb = w * 32 + i * 8;
      const int sg = sg0 ^ ((rb >> 3) & 3);
      gld16(Ab + (size_t)(rb + srow) * DM + k0 + sg * 8, &As[rb * 64]);
      gld16(Bb + (size_t)(rb + srow) * DM + k0 + sg * 8, &Bs[rb * 64]);
    }
    __syncthreads();
    #pragma unroll
    for (int c = 0; c < 2; ++c) {
      bf16x8 af[4], bg[4];
      #pragma unroll
      for (int i = 0; i < 4; ++i) {
        const int row = waveM * 64 + i * 16 + col;
        const int gp = (c * 4 + quad) ^ (row & 7) ^ ((row >> 3) & 3);
        af[i] = *(const bf16x8*)&As[row * 64 + gp * 8];
      }
      #pragma unroll
      for (int j = 0; j < 4; ++j) {
        const int row = waveN * 64 + j * 16 + col;
        const int gp = (c * 4 + quad) ^ (row & 7) ^ ((row >> 3) & 3);
        bg[j] = *(const bf16x8*)&Bs[row * 64 + gp * 8];
      }
      #pragma unroll
      for (int i = 0; i < 4; ++i) {
        #pragma unroll
        for (int j = 0; j < 4; ++j)
          acc[i][j] = __builtin_amdgcn_mfma_f32_16x16x32_bf16(af[i], bg[j], acc[i][j], 0, 0, 0);
      }
    }
    __syncthreads();
  }
}

// ---- dual-A 128x128 NT-GEMM core: C1 = Aq x B, C2 = Ak x B, shared B -------
// Stages 3 panels (Wq, Wk, x) per K-step instead of 4 for two separate
// blocks; 64 MFMA per K-step per wave. LDS = 48KB.
__device__ __forceinline__ void gemm_core_qk(
    u16* lds, const u16* __restrict__ Aq, const u16* __restrict__ Ak,
    const u16* __restrict__ Bb, f32x4 accQ[4][4], f32x4 accK[4][4])
{
  u16* As = lds;            // Wq tile [128][64]
  u16* A2 = lds + 8192;     // Wk tile [128][64]
  u16* Bs = lds + 16384;    // x  tile [128][64]
  const int tid = threadIdx.x, lane = tid & 63, w = tid >> 6;
  const int waveM = w >> 1, waveN = w & 1;
  const int col = lane & 15, quad = lane >> 4;
  const int srow = lane >> 3;
  const int sg0  = (lane & 7) ^ srow;

  for (int k0 = 0; k0 < DM; k0 += 64) {
    #pragma unroll
    for (int i = 0; i < 4; ++i) {
      const int rb = w * 32 + i * 8;
      const int sg = sg0 ^ ((rb >> 3) & 3);
      const size_t off = (size_t)(rb + srow) * DM + k0 + sg * 8;
      gld16(Aq + off, &As[rb * 64]);
      gld16(Ak + off, &A2[rb * 64]);
      gld16(Bb + off, &Bs[rb * 64]);
    }
    __syncthreads();
    #pragma unroll
    for (int c = 0; c < 2; ++c) {
      bf16x8 af[4], ag[4], bg[4];
      #pragma unroll
      for (int i = 0; i < 4; ++i) {
        const int row = waveM * 64 + i * 16 + col;
        const int gp = (c * 4 + quad) ^ (row & 7) ^ ((row >> 3) & 3);
        af[i] = *(const bf16x8*)&As[row * 64 + gp * 8];
        ag[i] = *(const bf16x8*)&A2[row * 64 + gp * 8];
      }
      #pragma unroll
      for (int j = 0; j < 4; ++j) {
        const int row = waveN * 64 + j * 16 + col;
        const int gp = (c * 4 + quad) ^ (row & 7) ^ ((row >> 3) & 3);
        bg[j] = *(const bf16x8*)&Bs[row * 64 + gp * 8];
      }
      #pragma unroll
      for (int i = 0; i < 4; ++i) {
        #pragma unroll
        for (int j = 0; j < 4; ++j) {
          accQ[i][j] = __builtin_amdgcn_mfma_f32_16x16x32_bf16(af[i], bg[j], accQ[i][j], 0, 0, 0);
          accK[i][j] = __builtin_amdgcn_mfma_f32_16x16x32_bf16(ag[i], bg[j], accK[i][j], 0, 0, 0);
        }
      }
    }
    __syncthreads();
  }
}

// ---------------- k2: fused QKV projection ----------------
// R19 grid (32, 8, 2) — token-block on x so XCD = token-group:
//   z=0: DUAL GEMM — A1 = Wq rows, A2 = Wk rows (cb: 128 channels),
//        B = x rows (tb: 128 tokens); writes Q (scaled) and K.
//   z=1: A = x rows (tb), B = Wv rows (cb) + transpose -> Vt.
__global__ __launch_bounds__(256, 2) void gemm_qkv_kernel(
    const u16* __restrict__ xb,
    const u16* __restrict__ Wqb, const u16* __restrict__ Wkb, const u16* __restrict__ Wvb,
    const float* __restrict__ bq, const float* __restrict__ bk, const float* __restrict__ bv,
    u16* __restrict__ Qs, u16* __restrict__ Kh, u16* __restrict__ Vt)
{
  __shared__ __align__(16) u16 smem[3 * 8192];   // 48 KB (z=1 uses 34 KB)
  const int z = blockIdx.z;
  const int tb = blockIdx.x;                     // token-block (32)
  const int cb = blockIdx.y;                     // channel-block (8)

  const int tid = threadIdx.x;
  const int lane = tid & 63, w = tid >> 6;
  const int waveM = w >> 1, waveN = w & 1;
  const int col = lane & 15, quad = lane >> 4;
  const f32x4 zf = {0.f, 0.f, 0.f, 0.f};

  if (z == 1) {                                  // ---- V path (R16 z=2) ----
    u16* tr = smem;
    f32x4 acc[4][4];
    #pragma unroll
    for (int i = 0; i < 4; ++i)
      #pragma unroll
      for (int j = 0; j < 4; ++j) acc[i][j] = zf;
    gemm_core_128x128(smem, xb + (size_t)(tb * 128) * DM,
                      Wvb + (size_t)(cb * 128) * DM, acc);
    // core ends with __syncthreads(); As/Bs dead -> reuse as transpose tile
    #pragma unroll
    for (int j = 0; j < 4; ++j) {
      const int cl = waveN * 64 + j * 16 + col;
      const float bb = bv[cb * 128 + cl];
      #pragma unroll
      for (int i = 0; i < 4; ++i) {
        const int tl = waveM * 64 + i * 16 + quad * 4;
        ushort4 pk;
        pk.x = f2bf(acc[i][j][0] + bb); pk.y = f2bf(acc[i][j][1] + bb);
        pk.z = f2bf(acc[i][j][2] + bb); pk.w = f2bf(acc[i][j][3] + bb);
        *(ushort4*)&tr[cl * 136 + tl] = pk;
      }
    }
    __syncthreads();
    const int t0 = tb * 128;
    const int b = t0 >> 11, sBase = t0 & 2047;
    #pragma unroll
    for (int rep = 0; rep < 8; ++rep) {
      const int chunk = rep * 256 + tid;
      const int row = chunk >> 4, off = (chunk & 15) * 8;
      const int c = cb * 128 + row;
      const int h = c >> 6, d = c & 63;
      uint4 v = *(const uint4*)&tr[row * 136 + off];
      *(uint4*)&Vt[((size_t)(b * NH + h) * DH + d) * SQ + sBase + off] = v;
    }
  } else {                                       // ---- fused Q+K path ----
    f32x4 accQ[4][4], accK[4][4];
    #pragma unroll
    for (int i = 0; i < 4; ++i)
      #pragma unroll
      for (int j = 0; j < 4; ++j) { accQ[i][j] = zf; accK[i][j] = zf; }
    gemm_core_qk(smem, Wqb + (size_t)(cb * 128) * DM,
                 Wkb + (size_t)(cb * 128) * DM,
                 xb + (size_t)(tb * 128) * DM, accQ, accK);
    const float qscale = 0.18033688011112042f;   // log2(e)/8 for Q
    const int chBase  = cb * 128 + waveM * 64;   // A side = channels
    const int tokBase = tb * 128 + waveN * 64;   // B side = tokens
    #pragma unroll
    for (int i = 0; i < 4; ++i) {
      const int c0 = chBase + i * 16 + quad * 4;         // 4 consecutive d
      const int hh = c0 >> 6, d0 = c0 & 63;
      const float4 bbq = *(const float4*)&bq[c0];
      const float4 bbk = *(const float4*)&bk[c0];
      #pragma unroll
      for (int j = 0; j < 4; ++j) {
        const int t = tokBase + j * 16 + col;
        const int b = t >> 11, s = t & 2047;
        const size_t base = ((size_t)(b * NH + hh) * SQ + s) * DH + d0;
        ushort4 pq;
        pq.x = f2bf((accQ[i][j][0] + bbq.x) * qscale);
        pq.y = f2bf((accQ[i][j][1] + bbq.y) * qscale);
        pq.z = f2bf((accQ[i][j][2] + bbq.z) * qscale);
        pq.w = f2bf((accQ[i][j][3] + bbq.w) * qscale);
        *(ushort4*)&Qs[base] = pq;
        ushort4 pk;
        pk.x = f2bf(accK[i][j][0] + bbk.x);
        pk.y = f2bf(accK[i][j][1] + bbk.y);
        pk.z = f2bf(accK[i][j][2] + bbk.z);
        pk.w = f2bf(accK[i][j][3] + bbk.w);
        *(ushort4*)&Kh[base] = pk;
      }
    }
  }
}

// ---------------- k4: flash attention, 32x32x16 MFMA, kt-tile 64 -------------
// REVERTED to R16 (proven 54.9us): grid (B*H, S/64) — bh on x so XCD = bh%8.
// block 256 = 4 waves. Wave w: qt = w&1 (q-half), st = w>>1 (s'-half).
// K/V double-buffered 8KB tiles (32KB total) -> 4 blocks/CU.
// Swizzle key(row) = (row&7)^((row>>3)&3). T5 setprio around MFMA.
__global__ __launch_bounds__(256, 4) void attn_kernel(
    const u16* __restrict__ Qs, const u16* __restrict__ Kh,
    const u16* __restrict__ Vt, u16* __restrict__ ctx)
{
  __shared__ __align__(16) char smem[33 * 1024];
  u16* KtB = (u16*)smem;                    // 2 x [64][64] swz, 4096 u16 each
  u16* VlB = (u16*)(smem + 16384);          // 2 x [64][64] swz, 4096 u16 each
  f32x4* red  = (f32x4*)smem;               // 32 KB, reused after kt loop
  float* lred = (float*)(smem + 32768);     // 1 KB

  const int tid = threadIdx.x, lane = tid & 63, w = tid >> 6;
  const int l31 = lane & 31, h = lane >> 5;
  const int qt = w & 1, st = w >> 1;
  const int bh = blockIdx.x, q0 = blockIdx.y * 64;
  const u16* Qb = Qs + ((size_t)bh * SQ + q0) * DH;
  const u16* Kb = Kh + (size_t)bh * SQ * DH;
  const u16* Vb = Vt + (size_t)bh * DH * SQ;
  const int srow = lane >> 3;               // staging row-in-group 0..7
  const int sgl  = (lane & 7) ^ srow;       // staging swizzle, rb part below

  // Q B-frags (only this wave's q-half): n = q = q0+qt*32+l31, k = 16ks+8h+j
  bf16x8 qreg[4];
  #pragma unroll
  for (int ks = 0; ks < 4; ++ks)
    qreg[ks] = *(const bf16x8*)(Qb + (size_t)(qt * 32 + l31) * DH + ks * 16 + h * 8);

  // stage tile 0 into buffer 0 (each wave: 16 rows of K, 16 rows of V)
  #pragma unroll
  for (int i = 0; i < 2; ++i) {
    const int rb = w * 16 + i * 8;
    const int sg = sgl ^ ((rb >> 3) & 3);
    gld16(Kb + (size_t)(rb + srow) * DH + sg * 8, &KtB[rb * 64]);
    gld16(Vb + (size_t)(rb + srow) * SQ + sg * 8, &VlB[rb * 64]);
  }

  f32x16 cacc[2];                    // [dt] partial ctx^T (64d x 32q)
  #pragma unroll
  for (int dt = 0; dt < 2; ++dt)
    #pragma unroll
    for (int e = 0; e < 16; ++e) cacc[dt][e] = 0.f;
  float l_s = 0.f;
  __syncthreads();

  for (int kt = 0; kt < SQ / 64; ++kt) {
    const int cur = kt & 1;
    u16* Kt = KtB + cur * 4096;
    u16* Vl = VlB + cur * 4096;
    if (kt + 1 < SQ / 64) {                // prefetch next tile into other buf
      const int nxt = cur ^ 1, s1 = (kt + 1) * 64;
      u16* Ktn = KtB + nxt * 4096;
      u16* Vln = VlB + nxt * 4096;
      #pragma unroll
      for (int i = 0; i < 2; ++i) {
        const int rb = w * 16 + i * 8;
        const int sg = sgl ^ ((rb >> 3) & 3);
        gld16(Kb + (size_t)(s1 + rb + srow) * DH + sg * 8, &Ktn[rb * 64]);
        gld16(Vb + (size_t)(rb + srow) * SQ + s1 + sg * 8, &Vln[rb * 64]);
      }
    }

    // S^T = K Q^T over wave's 32-s' slice (rows st*32..+32)
    f32x16 sacc;
    #pragma unroll
    for (int e = 0; e < 16; ++e) sacc[e] = 0.f;
    __builtin_amdgcn_s_setprio(1);
    #pragma unroll
    for (int ks = 0; ks < 4; ++ks) {
      const int row = st * 32 + l31;
      const int gp = (2 * ks + h) ^ (l31 & 7) ^ ((l31 >> 3) & 3);
      bf16x8 kf = *(const bf16x8*)&Kt[row * 64 + gp * 8];
      sacc = __builtin_amdgcn_mfma_f32_32x32x16_bf16(kf, qreg[ks], sacc, 0, 0, 0);
    }
    __builtin_amdgcn_s_setprio(0);

    // softmax p = exp2(s); Pp[rg][u] covers s'loc = 8rg + 4h + 2u + {0,1}
    u32 Pp[4][2];
    {
      float p[16];
      #pragma unroll
      for (int e = 0; e < 16; ++e)
        p[e] = __builtin_amdgcn_exp2f(sacc[e]);
      float t0 = (p[0] + p[1]) + (p[2] + p[3]);
      float t1 = (p[4] + p[5]) + (p[6] + p[7]);
      float t2 = (p[8] + p[9]) + (p[10] + p[11]);
      float t3 = (p[12] + p[13]) + (p[14] + p[15]);
      l_s += (t0 + t1) + (t2 + t3);
      #pragma unroll
      for (int rg = 0; rg < 4; ++rg) {
        Pp[rg][0] = pk2bf(p[4 * rg + 0], p[4 * rg + 1]);
        Pp[rg][1] = pk2bf(p[4 * rg + 2], p[4 * rg + 3]);
      }
    }

    // ctx^T += V^T(slice) P^T(slice): 2 ksteps over the 32 s'
    __builtin_amdgcn_s_setprio(1);
    #pragma unroll
    for (int ks = 0; ks < 2; ++ks) {
      u32 own0 = h ? Pp[2 * ks + 1][0] : Pp[2 * ks][0];
      u32 own1 = h ? Pp[2 * ks + 1][1] : Pp[2 * ks][1];
      u32 snd0 = h ? Pp[2 * ks][0] : Pp[2 * ks + 1][0];
      u32 snd1 = h ? Pp[2 * ks][1] : Pp[2 * ks + 1][1];
      u32 rcv0 = (u32)__shfl_xor((int)snd0, 32, 64);
      u32 rcv1 = (u32)__shfl_xor((int)snd1, 32, 64);
      u32x4 fw;
      fw.x = h ? rcv0 : own0;
      fw.y = h ? rcv1 : own1;
      fw.z = h ? own0 : rcv0;
      fw.w = h ? own1 : rcv1;
      bf16x8 pf = __builtin_bit_cast(bf16x8, fw);
      #pragma unroll
      for (int dt = 0; dt < 2; ++dt) {
        const int row = dt * 32 + l31;
        const int gp = (4 * st + 2 * ks + h) ^ (l31 & 7) ^ ((l31 >> 3) & 3);
        bf16x8 vf = *(const bf16x8*)&Vl[row * 64 + gp * 8];
        cacc[dt] = __builtin_amdgcn_mfma_f32_32x32x16_bf16(vf, pf, cacc[dt], 0, 0, 0);
      }
    }
    __builtin_amdgcn_s_setprio(0);
    __syncthreads();   // buffer-swap fence + prefetch drain
  }

  // ----- cross-wave reduction (2 sources per output) + epilogue -----
  float lq = l_s + __shfl_xor(l_s, 32, 64);
  if (h == 0) lred[w * 32 + l31] = lq;
  #pragma unroll
  for (int dt = 0; dt < 2; ++dt) {
    #pragma unroll
    for (int c = 0; c < 4; ++c) {
      f32x4 ch;
      ch[0] = cacc[dt][4 * c + 0]; ch[1] = cacc[dt][4 * c + 1];
      ch[2] = cacc[dt][4 * c + 2]; ch[3] = cacc[dt][4 * c + 3];
      red[((w * 2 + dt) * 4 + c) * 64 + lane] = ch;
    }
  }
  __syncthreads();
  // wave w outputs qt' = w&1, d-slice dt' = w>>1; sources: waves qt', qt'+2
  const int qt2 = w & 1, dt2 = w >> 1;
  const int b = bh >> 4, hd = bh & 15;
  const float lsum = lred[qt2 * 32 + l31] + lred[(2 + qt2) * 32 + l31];
  const float inv = 1.0f / lsum;
  const int s = q0 + qt2 * 32 + l31;
  #pragma unroll
  for (int c = 0; c < 4; ++c) {
    f32x4 sum = red[((qt2 * 2 + dt2) * 4 + c) * 64 + lane];
    sum += red[(((2 + qt2) * 2 + dt2) * 4 + c) * 64 + lane];
    const int d0 = dt2 * 32 + c * 8 + 4 * h;
    ushort4 pk;
    pk.x = f2bf(sum[0] * inv); pk.y = f2bf(sum[1] * inv);
    pk.z = f2bf(sum[2] * inv); pk.w = f2bf(sum[3] * inv);
    *(ushort4*)&ctx[(size_t)(b * SQ + s) * DM + hd * DH + d0] = pk;
  }
}

// ------------- 128x64 NT-GEMM core (A=128 rows, B=64 rows, BK=64) ------------
__device__ __forceinline__ void gemm_core_128x64(
    u16* lds, const u16* __restrict__ Ab, const u16* __restrict__ Bb,
    f32x4 acc[4][2])
{
  u16* As = lds;            // [128][64]
  u16* Bs = lds + 8192;     // [64][64]
  const int tid = threadIdx.x, lane = tid & 63, w = tid >> 6;
  const int waveM = w >> 1, waveN = w & 1;
  const int col = lane & 15, quad = lane >> 4;
  const int srow = lane >> 3;
  const int sg0  = (lane & 7) ^ srow;

  for (int k0 = 0; k0 < DM; k0 += 64) {
    #pragma unroll
    for (int i = 0; i < 4; ++i) {
      const int rb = w * 32 + i * 8;
      const int sg = sg0 ^ ((rb >> 3) & 3);
      gld16(Ab + (size_t)(rb + srow) * DM + k0 + sg * 8, &As[rb * 64]);
    }
    #pragma unroll
    for (int i = 0; i < 2; ++i) {
      const int rb = w * 16 + i * 8;
      const int sg = sg0 ^ ((rb >> 3) & 3);
      gld16(Bb + (size_t)(rb + srow) * DM + k0 + sg * 8, &Bs[rb * 64]);
    }
    __syncthreads();
    #pragma unroll
    for (int c = 0; c < 2; ++c) {
      bf16x8 af[4], bg[2];
      #pragma unroll
      for (int i = 0; i < 4; ++i) {
        const int row = waveM * 64 + i * 16 + col;
        const int gp = (c * 4 + quad) ^ (row & 7) ^ ((row >> 3) & 3);
        af[i] = *(const bf16x8*)&As[row * 64 + gp * 8];
      }
      #pragma unroll
      for (int j = 0; j < 2; ++j) {
        const int row = waveN * 32 + j * 16 + col;
        const int gp = (c * 4 + quad) ^ (row & 7) ^ ((row >> 3) & 3);
        bg[j] = *(const bf16x8*)&Bs[row * 64 + gp * 8];
      }
      #pragma unroll
      for (int i = 0; i < 4; ++i) {
        #pragma unroll
        for (int j = 0; j < 2; ++j)
          acc[i][j] = __builtin_amdgcn_mfma_f32_16x16x32_bf16(af[i], bg[j], acc[i][j], 0, 0, 0);
      }
    }
    __syncthreads();
  }
}

// -------- k5: output projection (128x64 tiles, BK=64 swizzled, fp32 out) -----
// grid (32, 16) — token-block on x so XCD = token-group.
__global__ __launch_bounds__(256) void gemm_out_kernel(
    const u16* __restrict__ ctx, const u16* __restrict__ Wob,
    const float* __restrict__ bo, float* __restrict__ out)
{
  __shared__ __align__(16) u16 smem[128 * 64 + 64 * 64];  // 24 KB
  const int tb = blockIdx.x;                 // token-block (32)
  const int cb = blockIdx.y;                 // channel-block (16)
  const int tid = threadIdx.x, lane = tid & 63, w = tid >> 6;
  const int waveM = w >> 1, waveN = w & 1;
  const int col = lane & 15, quad = lane >> 4;

  f32x4 acc[4][2];
  const f32x4 zf = {0.f, 0.f, 0.f, 0.f};
  #pragma unroll
  for (int i = 0; i < 4; ++i) {
    #pragma unroll
    for (int j = 0; j < 2; ++j) acc[i][j] = zf;
  }

  gemm_core_128x64(smem, ctx + (size_t)(tb * 128) * DM,
                   Wob + (size_t)(cb * 64) * DM, acc);

  const int rowBase = tb * 128 + waveM * 64;   // A side = tokens
  const int colBase = cb * 64 + waveN * 32;    // B side = channels
  #pragma unroll
  for (int j = 0; j < 2; ++j) {
    const int c = colBase + j * 16 + col;
    const float bb = bo[c];
    #pragma unroll
    for (int i = 0; i < 4; ++i) {
      #pragma unroll
      for (int r = 0; r < 4; ++r) {
        const int t = rowBase + i * 16 + quad * 4 + r;
        out[(size_t)t * DM + c] = acc[i][j][r] + bb;
      }
    }
  }
}

extern "C" void kernel_launch(void* const* d_in, const int* in_sizes, int n_in,
                              void* d_out, int out_size, void* d_ws, size_t ws_size,
                              hipStream_t stream) {
  const float* x  = (const float*)d_in[0];
  const float* Wq = (const float*)d_in[1];
  const float* bq = (const float*)d_in[2];
  const float* Wk = (const float*)d_in[3];
  const float* bk = (const float*)d_in[4];
  const float* Wv = (const float*)d_in[5];
  const float* bv = (const float*)d_in[6];
  const float* Wo = (const float*)d_in[7];
  const float* bo = (const float*)d_in[8];

  char* ws = (char*)d_ws;                  // 40 MB used
  u16* xb  = (u16*)(ws);                   // 8 MB  (reused as ctx after QKV)
  u16* Wqb = (u16*)(ws + (8ull  << 20));   // 2 MB
  u16* Wkb = (u16*)(ws + (10ull << 20));   // 2 MB
  u16* Wvb = (u16*)(ws + (12ull << 20));   // 2 MB
  u16* Wob = (u16*)(ws + (14ull << 20));   // 2 MB
  u16* Qs  = (u16*)(ws + (16ull << 20));   // 8 MB  [b,h,s,d], pre-scaled
  u16* Kh  = (u16*)(ws + (24ull << 20));   // 8 MB  [b,h,s,d]
  u16* Vt  = (u16*)(ws + (32ull << 20));   // 8 MB  [b,h,d,s]
  u16* ctx = xb;                           // alias: xb dead after QKV GEMM

  cast_bf16_kernel<<<dim3(256, 5), 256, 0, stream>>>(x, Wq, Wk, Wv, Wo,
                                                     xb, Wqb, Wkb, Wvb, Wob);
  gemm_qkv_kernel<<<dim3(32, 8, 2), 256, 0, stream>>>(xb, Wqb, Wkb, Wvb,
                                                      bq, bk, bv, Qs, Kh, Vt);
  attn_kernel<<<dim3(32, 32), 256, 0, stream>>>(Qs, Kh, Vt, ctx);
  gemm_out_kernel<<<dim3(32, 16), 256, 0, stream>>>(ctx, Wob, bo, (float*)d_out);
  (void)in_sizes; (void)n_in; (void)out_size; (void)ws_size;
}

// Round 6
// 180.065 us; speedup vs baseline: 1.4995x; 1.0484x over previous
//
#include <hip/hip_runtime.h>

// MultiHeadSelfAttention: B=2, S=2048, D=1024, H=16, Dh=64, fp32 in/out.
// R20: attn q-tile 64->128 (amortization, the inverse of R17/R18's error):
// each wave owns a full 32q x 64s' slice (no st-split) -> 16 MFMA per wave
// per staged tile (2x R16), epilogue cross-wave reduction DELETED (cacc is
// final per wave; direct store), l_s final per lane, P-exchange via
// v_permlane32_swap (correctness-proven in R17/R18). Same staging code,
// same swizzle keys (verified: (32+l31)&7 = l31&7, ((32+l31)>>3)&3 =
// (l31>>3)&3). Grid (32,16) = 512 blocks, 32KB LDS, 2 blocks/CU.
// cast/qkv(R19 dual Q+K)/out byte-identical to R19 (controls).

#define T_TOK 4096
#define DM    1024
#define SQ    2048
#define NH    16
#define DH    64

typedef unsigned short u16;
typedef unsigned int   u32;
typedef __bf16 bf16x8 __attribute__((ext_vector_type(8)));
typedef float  f32x4  __attribute__((ext_vector_type(4)));
typedef float  f32x16 __attribute__((ext_vector_type(16)));
typedef u32    u32x4  __attribute__((ext_vector_type(4)));

__device__ __forceinline__ u16 f2bf(float f) {   // RNE fp32->bf16
  u32 u = __builtin_bit_cast(u32, f);
  u32 r = (u + 0x7FFFu + ((u >> 16) & 1u)) >> 16;
  return (u16)r;
}

#if __has_builtin(__builtin_amdgcn_cvt_pk_bf16_f32)
typedef __bf16 bf16x2 __attribute__((ext_vector_type(2)));
__device__ __forceinline__ u32 pk2bf(float a, float b) {
  bf16x2 h = __builtin_amdgcn_cvt_pk_bf16_f32(a, b);
  return __builtin_bit_cast(u32, h);
}
#else
__device__ __forceinline__ u32 pk2bf(float a, float b) {  // 1 instr on gfx950
  u32 r;
  asm("v_cvt_pk_bf16_f32 %0, %1, %2" : "=v"(r) : "v"(a), "v"(b));
  return r;
}
#endif

__device__ __forceinline__ void gld16(const void* g, void* l) {
  __builtin_amdgcn_global_load_lds(
      (const __attribute__((address_space(1))) u32*)g,
      (__attribute__((address_space(3))) u32*)l, 16, 0, 0);
}

// ---------------- k1: cast to bf16 ----------------
__global__ void cast_bf16_kernel(const float* __restrict__ x,
    const float* __restrict__ w0, const float* __restrict__ w1,
    const float* __restrict__ w2, const float* __restrict__ w3,
    u16* __restrict__ xb, u16* __restrict__ o0, u16* __restrict__ o1,
    u16* __restrict__ o2, u16* __restrict__ o3)
{
  const float* src; u16* dst; int n;
  switch (blockIdx.y) {
    case 0:  src = x;  dst = xb; n = T_TOK * DM; break;
    case 1:  src = w0; dst = o0; n = DM * DM; break;
    case 2:  src = w1; dst = o1; n = DM * DM; break;
    case 3:  src = w2; dst = o2; n = DM * DM; break;
    default: src = w3; dst = o3; n = DM * DM; break;
  }
  const int stride = gridDim.x * blockDim.x;
  for (int i = blockIdx.x * blockDim.x + threadIdx.x; i * 4 < n; i += stride) {
    float4 v = ((const float4*)src)[i];
    ushort4 o;
    o.x = f2bf(v.x); o.y = f2bf(v.y); o.z = f2bf(v.z); o.w = f2bf(v.w);
    ((ushort4*)dst)[i] = o;
  }
}

// ------------- shared 128x128 NT-GEMM core (K=1024, BK=64, swizzled) ---------
__device__ __forceinline__ void gemm_core_128x128(
    u16* lds, const u16* __restrict__ Ab, const u16* __restrict__ Bb,
    f32x4 acc[4][4])
{
  u16* As = lds;
  u16* Bs = lds + 8192;
  const int tid = threadIdx.x, lane = tid & 63, w = tid >> 6;
  const int waveM = w >> 1, waveN = w & 1;
  const int col = lane & 15, quad = lane >> 4;
  const int srow = lane >> 3;                  // 0..7
  const int sg0  = (lane & 7) ^ srow;          // swizzle, rb-part added below

  for (int k0 = 0; k0 < DM; k0 += 64) {
    #pragma unroll
    for (int i = 0; i < 4; ++i) {
      const int rb = w * 32 + i * 8;
      const int sg = sg0 ^ ((rb >> 3) & 3);
      gld16(Ab + (size_t)(rb + srow) * DM + k0 + sg * 8, &As[rb * 64]);
      gld16(Bb + (size_t)(rb + srow) * DM + k0 + sg * 8, &Bs[rb * 64]);
    }
    __syncthreads();
    #pragma unroll
    for (int c = 0; c < 2; ++c) {
      bf16x8 af[4], bg[4];
      #pragma unroll
      for (int i = 0; i < 4; ++i) {
        const int row = waveM * 64 + i * 16 + col;
        const int gp = (c * 4 + quad) ^ (row & 7) ^ ((row >> 3) & 3);
        af[i] = *(const bf16x8*)&As[row * 64 + gp * 8];
      }
      #pragma unroll
      for (int j = 0; j < 4; ++j) {
        const int row = waveN * 64 + j * 16 + col;
        const int gp = (c * 4 + quad) ^ (row & 7) ^ ((row >> 3) & 3);
        bg[j] = *(const bf16x8*)&Bs[row * 64 + gp * 8];
      }
      #pragma unroll
      for (int i = 0; i < 4; ++i) {
        #pragma unroll
        for (int j = 0; j < 4; ++j)
          acc[i][j] = __builtin_amdgcn_mfma_f32_16x16x32_bf16(af[i], bg[j], acc[i][j], 0, 0, 0);
      }
    }
    __syncthreads();
  }
}

// ---- dual-A 128x128 NT-GEMM core: C1 = Aq x B, C2 = Ak x B, shared B -------
__device__ __forceinline__ void gemm_core_qk(
    u16* lds, const u16* __restrict__ Aq, const u16* __restrict__ Ak,
    const u16* __restrict__ Bb, f32x4 accQ[4][4], f32x4 accK[4][4])
{
  u16* As = lds;            // Wq tile [128][64]
  u16* A2 = lds + 8192;     // Wk tile [128][64]
  u16* Bs = lds + 16384;    // x  tile [128][64]
  const int tid = threadIdx.x, lane = tid & 63, w = tid >> 6;
  const int waveM = w >> 1, waveN = w & 1;
  const int col = lane & 15, quad = lane >> 4;
  const int srow = lane >> 3;
  const int sg0  = (lane & 7) ^ srow;

  for (int k0 = 0; k0 < DM; k0 += 64) {
    #pragma unroll
    for (int i = 0; i < 4; ++i) {
      const int rb = w * 32 + i * 8;
      const int sg = sg0 ^ ((rb >> 3) & 3);
      const size_t off = (size_t)(rb + srow) * DM + k0 + sg * 8;
      gld16(Aq + off, &As[rb * 64]);
      gld16(Ak + off, &A2[rb * 64]);
      gld16(Bb + off, &Bs[rb * 64]);
    }
    __syncthreads();
    #pragma unroll
    for (int c = 0; c < 2; ++c) {
      bf16x8 af[4], ag[4], bg[4];
      #pragma unroll
      for (int i = 0; i < 4; ++i) {
        const int row = waveM * 64 + i * 16 + col;
        const int gp = (c * 4 + quad) ^ (row & 7) ^ ((row >> 3) & 3);
        af[i] = *(const bf16x8*)&As[row * 64 + gp * 8];
        ag[i] = *(const bf16x8*)&A2[row * 64 + gp * 8];
      }
      #pragma unroll
      for (int j = 0; j < 4; ++j) {
        const int row = waveN * 64 + j * 16 + col;
        const int gp = (c * 4 + quad) ^ (row & 7) ^ ((row >> 3) & 3);
        bg[j] = *(const bf16x8*)&Bs[row * 64 + gp * 8];
      }
      #pragma unroll
      for (int i = 0; i < 4; ++i) {
        #pragma unroll
        for (int j = 0; j < 4; ++j) {
          accQ[i][j] = __builtin_amdgcn_mfma_f32_16x16x32_bf16(af[i], bg[j], accQ[i][j], 0, 0, 0);
          accK[i][j] = __builtin_amdgcn_mfma_f32_16x16x32_bf16(ag[i], bg[j], accK[i][j], 0, 0, 0);
        }
      }
    }
    __syncthreads();
  }
}

// ---------------- k2: fused QKV projection ----------------
// grid (32, 8, 2) — token-block on x so XCD = token-group:
//   z=0: DUAL GEMM — Wq+Wk share the staged x-tile; writes Q (scaled), K.
//   z=1: A = x rows (tb), B = Wv rows (cb) + transpose -> Vt.
__global__ __launch_bounds__(256, 2) void gemm_qkv_kernel(
    const u16* __restrict__ xb,
    const u16* __restrict__ Wqb, const u16* __restrict__ Wkb, const u16* __restrict__ Wvb,
    const float* __restrict__ bq, const float* __restrict__ bk, const float* __restrict__ bv,
    u16* __restrict__ Qs, u16* __restrict__ Kh, u16* __restrict__ Vt)
{
  __shared__ __align__(16) u16 smem[3 * 8192];   // 48 KB (z=1 uses 34 KB)
  const int z = blockIdx.z;
  const int tb = blockIdx.x;                     // token-block (32)
  const int cb = blockIdx.y;                     // channel-block (8)

  const int tid = threadIdx.x;
  const int lane = tid & 63, w = tid >> 6;
  const int waveM = w >> 1, waveN = w & 1;
  const int col = lane & 15, quad = lane >> 4;
  const f32x4 zf = {0.f, 0.f, 0.f, 0.f};

  if (z == 1) {                                  // ---- V path ----
    u16* tr = smem;
    f32x4 acc[4][4];
    #pragma unroll
    for (int i = 0; i < 4; ++i)
      #pragma unroll
      for (int j = 0; j < 4; ++j) acc[i][j] = zf;
    gemm_core_128x128(smem, xb + (size_t)(tb * 128) * DM,
                      Wvb + (size_t)(cb * 128) * DM, acc);
    #pragma unroll
    for (int j = 0; j < 4; ++j) {
      const int cl = waveN * 64 + j * 16 + col;
      const float bb = bv[cb * 128 + cl];
      #pragma unroll
      for (int i = 0; i < 4; ++i) {
        const int tl = waveM * 64 + i * 16 + quad * 4;
        ushort4 pk;
        pk.x = f2bf(acc[i][j][0] + bb); pk.y = f2bf(acc[i][j][1] + bb);
        pk.z = f2bf(acc[i][j][2] + bb); pk.w = f2bf(acc[i][j][3] + bb);
        *(ushort4*)&tr[cl * 136 + tl] = pk;
      }
    }
    __syncthreads();
    const int t0 = tb * 128;
    const int b = t0 >> 11, sBase = t0 & 2047;
    #pragma unroll
    for (int rep = 0; rep < 8; ++rep) {
      const int chunk = rep * 256 + tid;
      const int row = chunk >> 4, off = (chunk & 15) * 8;
      const int c = cb * 128 + row;
      const int h = c >> 6, d = c & 63;
      uint4 v = *(const uint4*)&tr[row * 136 + off];
      *(uint4*)&Vt[((size_t)(b * NH + h) * DH + d) * SQ + sBase + off] = v;
    }
  } else {                                       // ---- fused Q+K path ----
    f32x4 accQ[4][4], accK[4][4];
    #pragma unroll
    for (int i = 0; i < 4; ++i)
      #pragma unroll
      for (int j = 0; j < 4; ++j) { accQ[i][j] = zf; accK[i][j] = zf; }
    gemm_core_qk(smem, Wqb + (size_t)(cb * 128) * DM,
                 Wkb + (size_t)(cb * 128) * DM,
                 xb + (size_t)(tb * 128) * DM, accQ, accK);
    const float qscale = 0.18033688011112042f;   // log2(e)/8 for Q
    const int chBase  = cb * 128 + waveM * 64;   // A side = channels
    const int tokBase = tb * 128 + waveN * 64;   // B side = tokens
    #pragma unroll
    for (int i = 0; i < 4; ++i) {
      const int c0 = chBase + i * 16 + quad * 4;         // 4 consecutive d
      const int hh = c0 >> 6, d0 = c0 & 63;
      const float4 bbq = *(const float4*)&bq[c0];
      const float4 bbk = *(const float4*)&bk[c0];
      #pragma unroll
      for (int j = 0; j < 4; ++j) {
        const int t = tokBase + j * 16 + col;
        const int b = t >> 11, s = t & 2047;
        const size_t base = ((size_t)(b * NH + hh) * SQ + s) * DH + d0;
        ushort4 pq;
        pq.x = f2bf((accQ[i][j][0] + bbq.x) * qscale);
        pq.y = f2bf((accQ[i][j][1] + bbq.y) * qscale);
        pq.z = f2bf((accQ[i][j][2] + bbq.z) * qscale);
        pq.w = f2bf((accQ[i][j][3] + bbq.w) * qscale);
        *(ushort4*)&Qs[base] = pq;
        ushort4 pk;
        pk.x = f2bf(accK[i][j][0] + bbk.x);
        pk.y = f2bf(accK[i][j][1] + bbk.y);
        pk.z = f2bf(accK[i][j][2] + bbk.z);
        pk.w = f2bf(accK[i][j][3] + bbk.w);
        *(ushort4*)&Kh[base] = pk;
      }
    }
  }
}

// ---------------- k4: flash attention, q-tile 128, full-s' waves ------------
// grid (B*H, S/128) — bh on x so XCD = bh%8 (K/V L2-resident).
// block 256 = 4 waves; wave w owns q slice q0 + w*32 .. +32 over the FULL
// 64-s' tile: per iter 8 QK MFMA (2 s'-halves) + 8 PV MFMA. cacc is final
// per wave -> direct store, no cross-wave reduction. P-exchange via
// v_permlane32_swap (verified R17/R18). K/V staged exactly as R16
// (double-buffered 8KB tiles, 32KB total), 2 blocks/CU.
__global__ __launch_bounds__(256, 2) void attn_kernel(
    const u16* __restrict__ Qs, const u16* __restrict__ Kh,
    const u16* __restrict__ Vt, u16* __restrict__ ctx)
{
  __shared__ __align__(16) char smem[32 * 1024];
  u16* KtB = (u16*)smem;                    // 2 x [64][64] swz, 4096 u16 each
  u16* VlB = (u16*)(smem + 16384);          // 2 x [64][64] swz, 4096 u16 each

  const int tid = threadIdx.x, lane = tid & 63, w = tid >> 6;
  const int l31 = lane & 31, h = lane >> 5;
  const int bh = blockIdx.x, q0 = blockIdx.y * 128;
  const u16* Qb = Qs + ((size_t)bh * SQ + q0) * DH;
  const u16* Kb = Kh + (size_t)bh * SQ * DH;
  const u16* Vb = Vt + (size_t)bh * DH * SQ;
  const int srow = lane >> 3;               // staging row-in-group 0..7
  const int sgl  = (lane & 7) ^ srow;       // staging swizzle, rb part below

  // Q B-frags (this wave's 32 q): n = q = q0 + w*32 + l31, k = 16ks+8h+j
  bf16x8 qreg[4];
  #pragma unroll
  for (int ks = 0; ks < 4; ++ks)
    qreg[ks] = *(const bf16x8*)(Qb + (size_t)(w * 32 + l31) * DH + ks * 16 + h * 8);

  // stage tile 0 into buffer 0 (each wave: 16 rows of K, 16 rows of V)
  #pragma unroll
  for (int i = 0; i < 2; ++i) {
    const int rb = w * 16 + i * 8;
    const int sg = sgl ^ ((rb >> 3) & 3);
    gld16(Kb + (size_t)(rb + srow) * DH + sg * 8, &KtB[rb * 64]);
    gld16(Vb + (size_t)(rb + srow) * SQ + sg * 8, &VlB[rb * 64]);
  }

  f32x16 cacc[2];                    // [dt] ctx^T (64d x 32q), FINAL per wave
  #pragma unroll
  for (int dt = 0; dt < 2; ++dt)
    #pragma unroll
    for (int e = 0; e < 16; ++e) cacc[dt][e] = 0.f;
  float l_s = 0.f;
  __syncthreads();

  for (int kt = 0; kt < SQ / 64; ++kt) {
    const int cur = kt & 1;
    u16* Kt = KtB + cur * 4096;
    u16* Vl = VlB + cur * 4096;
    if (kt + 1 < SQ / 64) {                // prefetch next tile into other buf
      const int nxt = cur ^ 1, s1 = (kt + 1) * 64;
      u16* Ktn = KtB + nxt * 4096;
      u16* Vln = VlB + nxt * 4096;
      #pragma unroll
      for (int i = 0; i < 2; ++i) {
        const int rb = w * 16 + i * 8;
        const int sg = sgl ^ ((rb >> 3) & 3);
        gld16(Kb + (size_t)(s1 + rb + srow) * DH + sg * 8, &Ktn[rb * 64]);
        gld16(Vb + (size_t)(rb + srow) * SQ + s1 + sg * 8, &Vln[rb * 64]);
      }
    }

    // S^T = K Q^T over BOTH 32-s' halves (keys for row 32+l31 ≡ row l31)
    f32x16 sacc0 = {}, sacc1 = {};
    __builtin_amdgcn_s_setprio(1);
    #pragma unroll
    for (int ks = 0; ks < 4; ++ks) {
      const int gp = ((2 * ks + h) ^ (l31 & 7) ^ ((l31 >> 3) & 3)) * 8;
      bf16x8 kf0 = *(const bf16x8*)&Kt[l31 * 64 + gp];
      bf16x8 kf1 = *(const bf16x8*)&Kt[(32 + l31) * 64 + gp];
      sacc0 = __builtin_amdgcn_mfma_f32_32x32x16_bf16(kf0, qreg[ks], sacc0, 0, 0, 0);
      sacc1 = __builtin_amdgcn_mfma_f32_32x32x16_bf16(kf1, qreg[ks], sacc1, 0, 0, 0);
    }
    __builtin_amdgcn_s_setprio(0);

    // softmax p = exp2(s), both halves; Pp[hs][rg][u]: s'loc = 32hs+8rg+4h+2u
    u32 Pp[2][4][2];
    {
      float p[16], q[16];
      #pragma unroll
      for (int e = 0; e < 16; ++e) {
        p[e] = __builtin_amdgcn_exp2f(sacc0[e]);
        q[e] = __builtin_amdgcn_exp2f(sacc1[e]);
      }
      float t0 = (p[0] + p[1]) + (p[2] + p[3]);
      float t1 = (p[4] + p[5]) + (p[6] + p[7]);
      float t2 = (p[8] + p[9]) + (p[10] + p[11]);
      float t3 = (p[12] + p[13]) + (p[14] + p[15]);
      float u0 = (q[0] + q[1]) + (q[2] + q[3]);
      float u1 = (q[4] + q[5]) + (q[6] + q[7]);
      float u2 = (q[8] + q[9]) + (q[10] + q[11]);
      float u3 = (q[12] + q[13]) + (q[14] + q[15]);
      l_s += ((t0 + t1) + (t2 + t3)) + ((u0 + u1) + (u2 + u3));
      #pragma unroll
      for (int rg = 0; rg < 4; ++rg) {
        Pp[0][rg][0] = pk2bf(p[4 * rg + 0], p[4 * rg + 1]);
        Pp[0][rg][1] = pk2bf(p[4 * rg + 2], p[4 * rg + 3]);
        Pp[1][rg][0] = pk2bf(q[4 * rg + 0], q[4 * rg + 1]);
        Pp[1][rg][1] = pk2bf(q[4 * rg + 2], q[4 * rg + 3]);
      }
    }

    // ctx^T += V^T P^T: 4 ksteps over 64 s' (ksg), both d-halves
    __builtin_amdgcn_s_setprio(1);
    #pragma unroll
    for (int ksg = 0; ksg < 4; ++ksg) {
      const int hs = ksg >> 1, p2 = ksg & 1;
      u32 a0 = Pp[hs][2 * p2][0], b0 = Pp[hs][2 * p2 + 1][0];
      u32 a1 = Pp[hs][2 * p2][1], b1 = Pp[hs][2 * p2 + 1][1];
      asm("v_permlane32_swap_b32 %0, %1" : "+v"(a0), "+v"(b0));
      asm("v_permlane32_swap_b32 %0, %1" : "+v"(a1), "+v"(b1));
      u32x4 fw;
      fw.x = a0; fw.y = a1; fw.z = b0; fw.w = b1;
      bf16x8 pf = __builtin_bit_cast(bf16x8, fw);
      const int gp = ((2 * ksg + h) ^ (l31 & 7) ^ ((l31 >> 3) & 3)) * 8;
      bf16x8 vf0 = *(const bf16x8*)&Vl[l31 * 64 + gp];
      bf16x8 vf1 = *(const bf16x8*)&Vl[(32 + l31) * 64 + gp];
      cacc[0] = __builtin_amdgcn_mfma_f32_32x32x16_bf16(vf0, pf, cacc[0], 0, 0, 0);
      cacc[1] = __builtin_amdgcn_mfma_f32_32x32x16_bf16(vf1, pf, cacc[1], 0, 0, 0);
    }
    __builtin_amdgcn_s_setprio(0);
    __syncthreads();   // buffer-swap fence + prefetch drain
  }

  // ----- epilogue: cacc is final per wave; direct scaled store -----
  const float lq = l_s + __shfl_xor(l_s, 32, 64);
  const float inv = 1.0f / lq;
  const int b = bh >> 4, hd = bh & 15;
  const int s = q0 + w * 32 + l31;
  #pragma unroll
  for (int dt = 0; dt < 2; ++dt) {
    #pragma unroll
    for (int c = 0; c < 4; ++c) {
      const int d0 = dt * 32 + c * 8 + 4 * h;
      ushort4 pk;
      pk.x = f2bf(cacc[dt][4 * c + 0] * inv);
      pk.y = f2bf(cacc[dt][4 * c + 1] * inv);
      pk.z = f2bf(cacc[dt][4 * c + 2] * inv);
      pk.w = f2bf(cacc[dt][4 * c + 3] * inv);
      *(ushort4*)&ctx[(size_t)(b * SQ + s) * DM + hd * DH + d0] = pk;
    }
  }
}

// ------------- 128x64 NT-GEMM core (A=128 rows, B=64 rows, BK=64) ------------
__device__ __forceinline__ void gemm_core_128x64(
    u16* lds, const u16* __restrict__ Ab, const u16* __restrict__ Bb,
    f32x4 acc[4][2])
{
  u16* As = lds;            // [128][64]
  u16* Bs = lds + 8192;     // [64][64]
  const int tid = threadIdx.x, lane = tid & 63, w = tid >> 6;
  const int waveM = w >> 1, waveN = w & 1;
  const int col = lane & 15, quad = lane >> 4;
  const int srow = lane >> 3;
  const int sg0  = (lane & 7) ^ srow;

  for (int k0 = 0; k0 < DM; k0 += 64) {
    #pragma unroll
    for (int i = 0; i < 4; ++i) {
      const int rb = w * 32 + i * 8;
      const int sg = sg0 ^ ((rb >> 3) & 3);
      gld16(Ab + (size_t)(rb + srow) * DM + k0 + sg * 8, &As[rb * 64]);
    }
    #pragma unroll
    for (int i = 0; i < 2; ++i) {
      const int rb = w * 16 + i * 8;
      const int sg = sg0 ^ ((rb >> 3) & 3);
      gld16(Bb + (size_t)(rb + srow) * DM + k0 + sg * 8, &Bs[rb * 64]);
    }
    __syncthreads();
    #pragma unroll
    for (int c = 0; c < 2; ++c) {
      bf16x8 af[4], bg[2];
      #pragma unroll
      for (int i = 0; i < 4; ++i) {
        const int row = waveM * 64 + i * 16 + col;
        const int gp = (c * 4 + quad) ^ (row & 7) ^ ((row >> 3) & 3);
        af[i] = *(const bf16x8*)&As[row * 64 + gp * 8];
      }
      #pragma unroll
      for (int j = 0; j < 2; ++j) {
        const int row = waveN * 32 + j * 16 + col;
        const int gp = (c * 4 + quad) ^ (row & 7) ^ ((row >> 3) & 3);
        bg[j] = *(const bf16x8*)&Bs[row * 64 + gp * 8];
      }
      #pragma unroll
      for (int i = 0; i < 4; ++i) {
        #pragma unroll
        for (int j = 0; j < 2; ++j)
          acc[i][j] = __builtin_amdgcn_mfma_f32_16x16x32_bf16(af[i], bg[j], acc[i][j], 0, 0, 0);
      }
    }
    __syncthreads();
  }
}

// -------- k5: output projection (128x64 tiles, BK=64 swizzled, fp32 out) -----
// grid (32, 16) — token-block on x so XCD = token-group.
__global__ __launch_bounds__(256) void gemm_out_kernel(
    const u16* __restrict__ ctx, const u16* __restrict__ Wob,
    const float* __restrict__ bo, float* __restrict__ out)
{
  __shared__ __align__(16) u16 smem[128 * 64 + 64 * 64];  // 24 KB
  const int tb = blockIdx.x;                 // token-block (32)
  const int cb = blockIdx.y;                 // channel-block (16)
  const int tid = threadIdx.x, lane = tid & 63, w = tid >> 6;
  const int waveM = w >> 1, waveN = w & 1;
  const int col = lane & 15, quad = lane >> 4;

  f32x4 acc[4][2];
  const f32x4 zf = {0.f, 0.f, 0.f, 0.f};
  #pragma unroll
  for (int i = 0; i < 4; ++i) {
    #pragma unroll
    for (int j = 0; j < 2; ++j) acc[i][j] = zf;
  }

  gemm_core_128x64(smem, ctx + (size_t)(tb * 128) * DM,
                   Wob + (size_t)(cb * 64) * DM, acc);

  const int rowBase = tb * 128 + waveM * 64;   // A side = tokens
  const int colBase = cb * 64 + waveN * 32;    // B side = channels
  #pragma unroll
  for (int j = 0; j < 2; ++j) {
    const int c = colBase + j * 16 + col;
    const float bb = bo[c];
    #pragma unroll
    for (int i = 0; i < 4; ++i) {
      #pragma unroll
      for (int r = 0; r < 4; ++r) {
        const int t = rowBase + i * 16 + quad * 4 + r;
        out[(size_t)t * DM + c] = acc[i][j][r] + bb;
      }
    }
  }
}

extern "C" void kernel_launch(void* const* d_in, const int* in_sizes, int n_in,
                              void* d_out, int out_size, void* d_ws, size_t ws_size,
                              hipStream_t stream) {
  const float* x  = (const float*)d_in[0];
  const float* Wq = (const float*)d_in[1];
  const float* bq = (const float*)d_in[2];
  const float* Wk = (const float*)d_in[3];
  const float* bk = (const float*)d_in[4];
  const float* Wv = (const float*)d_in[5];
  const float* bv = (const float*)d_in[6];
  const float* Wo = (const float*)d_in[7];
  const float* bo = (const float*)d_in[8];

  char* ws = (char*)d_ws;                  // 40 MB used
  u16* xb  = (u16*)(ws);                   // 8 MB  (reused as ctx after QKV)
  u16* Wqb = (u16*)(ws + (8ull  << 20));   // 2 MB
  u16* Wkb = (u16*)(ws + (10ull << 20));   // 2 MB
  u16* Wvb = (u16*)(ws + (12ull << 20));   // 2 MB
  u16* Wob = (u16*)(ws + (14ull << 20));   // 2 MB
  u16* Qs  = (u16*)(ws + (16ull << 20));   // 8 MB  [b,h,s,d], pre-scaled
  u16* Kh  = (u16*)(ws + (24ull << 20));   // 8 MB  [b,h,s,d]
  u16* Vt  = (u16*)(ws + (32ull << 20));   // 8 MB  [b,h,d,s]
  u16* ctx = xb;                           // alias: xb dead after QKV GEMM

  cast_bf16_kernel<<<dim3(256, 5), 256, 0, stream>>>(x, Wq, Wk, Wv, Wo,
                                                     xb, Wqb, Wkb, Wvb, Wob);
  gemm_qkv_kernel<<<dim3(32, 8, 2), 256, 0, stream>>>(xb, Wqb, Wkb, Wvb,
                                                      bq, bk, bv, Qs, Kh, Vt);
  attn_kernel<<<dim3(32, 16), 256, 0, stream>>>(Qs, Kh, Vt, ctx);
  gemm_out_kernel<<<dim3(32, 16), 256, 0, stream>>>(ctx, Wob, bo, (float*)d_out);
  (void)in_sizes; (void)n_in; (void)out_size; (void)ws_size;
}